// Round 6
// baseline (380.272 us; speedup 1.0000x reference)
//
#include <hip/hip_runtime.h>
#include <hip/hip_bf16.h>

#define N_NODES 50000
#define N_EDGES 1600000
#define F_IN    512
#define F_HID   128
#define F_OUT   64
#define NBUK    391          // ceil(50000/128) buckets of 128 nodes
#define EPB     8192         // edges per block in bucket passes
#define CAP     4864         // per-bucket slot capacity (mean 4092, +12 sigma)

typedef short bf16x8 __attribute__((ext_vector_type(8)));
typedef float f32x4  __attribute__((ext_vector_type(4)));

__device__ __forceinline__ short f32_to_bf16(float f) {
    unsigned u = __float_as_uint(f);
    u += 0x7FFF + ((u >> 16) & 1);          // RTNE
    return (short)(u >> 16);
}
__device__ __forceinline__ float bf16_to_f32(short s) {
    return __uint_as_float(((unsigned)(unsigned short)s) << 16);
}
__device__ __forceinline__ float bf16lo(unsigned u) { return __uint_as_float(u << 16); }
__device__ __forceinline__ float bf16hi(unsigned u) { return __uint_as_float(u & 0xFFFF0000u); }

// 8x f32 -> bf16x8 via packed HW convert (RNE); 4 instrs instead of 24.
__device__ __forceinline__ bf16x8 cvt8(float4 lo, float4 hi) {
    union { unsigned u[4]; bf16x8 v; } r;
    asm("v_cvt_pk_bf16_f32 %0, %1, %2" : "=v"(r.u[0]) : "v"(lo.x), "v"(lo.y));
    asm("v_cvt_pk_bf16_f32 %0, %1, %2" : "=v"(r.u[1]) : "v"(lo.z), "v"(lo.w));
    asm("v_cvt_pk_bf16_f32 %0, %1, %2" : "=v"(r.u[2]) : "v"(hi.x), "v"(hi.y));
    asm("v_cvt_pk_bf16_f32 %0, %1, %2" : "=v"(r.u[3]) : "v"(hi.z), "v"(hi.w));
    return r.v;
}

// ---------------- CSR build: bucket partition with fixed-capacity slots ----------------

__global__ __launch_bounds__(256) void part_a(const int* __restrict__ dst,
                                              const int* __restrict__ src,
                                              const float* __restrict__ w,
                                              int* __restrict__ gcnt,
                                              uint2* __restrict__ tmp, int E) {
    __shared__ int h[NBUK];
    __shared__ int base[NBUK];
    for (int i = threadIdx.x; i < NBUK; i += 256) h[i] = 0;
    __syncthreads();
    int e0 = blockIdx.x * EPB;
    int e1 = min(e0 + EPB, E);
    for (int e = e0 + threadIdx.x; e < e1; e += 256)
        atomicAdd(&h[dst[e] >> 7], 1);
    __syncthreads();
    for (int i = threadIdx.x; i < NBUK; i += 256) {
        int c = h[i];
        base[i] = c ? atomicAdd(&gcnt[i], c) : 0;
        h[i] = 0;
    }
    __syncthreads();
    for (int e = e0 + threadIdx.x; e < e1; e += 256) {
        int d = dst[e];
        int b = d >> 7;
        int off = base[b] + atomicAdd(&h[b], 1);
        if (off < CAP)
            tmp[(size_t)b * CAP + off] = make_uint2(((unsigned)d << 16) | (unsigned)src[e],
                                                    __float_as_uint(w[e]));
    }
}

__global__ __launch_bounds__(256) void part_b(const uint2* __restrict__ tmp,
                                              const int* __restrict__ gcnt,
                                              int2* __restrict__ rowinfo,
                                              uint2* __restrict__ erec) {
    __shared__ int s[128];
    __shared__ int cur[128];
    int b = blockIdx.x, tid = threadIdx.x;
    int nb0 = b << 7;
    int r0 = b * CAP;
    int cnt_b = min(gcnt[b], CAP);
    int r1 = r0 + cnt_b;
    if (tid < 128) s[tid] = 0;
    __syncthreads();
    for (int i = r0 + tid; i < r1; i += 256)
        atomicAdd(&s[(tmp[i].x >> 16) - nb0], 1);
    __syncthreads();
    int v = (tid < 128) ? s[tid] : 0;
    #pragma unroll
    for (int off = 1; off < 128; off <<= 1) {
        int t = (tid >= off && tid < 128) ? s[tid - off] : 0;
        __syncthreads();
        if (tid < 128) s[tid] += t;
        __syncthreads();
    }
    if (tid < 128) {
        int ex = r0 + s[tid] - v;
        cur[tid] = ex;
        int node = nb0 + tid;
        if (node < N_NODES) rowinfo[node] = make_int2(ex, ex + v);
    }
    __syncthreads();
    for (int i = r0 + tid; i < r1; i += 256) {
        uint2 rec = tmp[i];
        int p = atomicAdd(&cur[(rec.x >> 16) - nb0], 1);
        erec[p] = make_uint2(rec.x & 0xFFFFu, rec.y);
    }
}

// ---------------- fragment-order conversions ----------------

// B fragment unit u = (kc*NT + nt)*64 + lane:
//   holds W[k = kc*32 + (lane>>4)*8 + j][n = nt*16 + (lane&15)]  (W is [KD][NC] row-major)
template<int KD, int NC>
__global__ void wtrans_frag(const float* __restrict__ W, bf16x8* __restrict__ Bfrag) {
    constexpr int KC = KD / 32, NT = NC / 16;
    int u = blockIdx.x * 256 + threadIdx.x;
    if (u >= KC * NT * 64) return;
    int lane = u & 63;
    int nt   = (u >> 6) % NT;
    int kc   = u / (64 * NT);
    int n = nt * 16 + (lane & 15);
    int k = kc * 32 + (lane >> 4) * 8;
    bf16x8 f;
    #pragma unroll
    for (int j = 0; j < 8; ++j) f[j] = f32_to_bf16(W[(size_t)(k + j) * NC + n]);
    Bfrag[u] = f;
}

// ------------- GEMM1: B-slice register-resident, A streamed from fp32 X -------------
// 4 waves/block = 4 N-slices (NTS=2 tiles = 32 cols each). Each wave loads its
// B-slice ONCE (KC*NTS = 32 bf16x8 = 128 VGPR) and loops over MLOOP m-tiles,
// streaming A with a PFA-deep prefetch pipeline + in-register cvt to bf16.
// All 4 waves of a block read the SAME A rows -> L2 dedup; B L2 traffic drops
// 1.6 GB -> ~100 MB vs the per-kc reload scheme.

template<int NC, int KD, int NTS, int MLOOP>
__global__ __launch_bounds__(256) void mfma_gemm_xr(const float* __restrict__ X,
                                                    const bf16x8* __restrict__ Bfrag,
                                                    short* __restrict__ C, int Mt) {
    constexpr int KC  = KD / 32;
    constexpr int NT  = NC / 16;
    constexpr int NSL = NT / NTS;            // n-slices per block (4 for GEMM1)
    constexpr int MW  = 4 / NSL;             // independent m-groups per block
    constexpr int PFA = (KC < 4) ? KC : 4;
    const int lane = threadIdx.x & 63;
    const int wave = threadIdx.x >> 6;
    const int ws   = wave % NSL;             // n-slice id
    const int wm   = wave / NSL;             // m-group id
    const int m0   = (blockIdx.x * MW + wm) * MLOOP;

    // B-slice -> registers, loaded exactly once (all indices compile-time)
    bf16x8 breg[KC * NTS];
    #pragma unroll
    for (int kc = 0; kc < KC; ++kc)
        #pragma unroll
        for (int nt = 0; nt < NTS; ++nt)
            breg[kc * NTS + nt] = Bfrag[((size_t)kc * NT + ws * NTS + nt) * 64 + lane];

    const int r_lo = lane & 15;              // row within 16-row tile
    const int cg   = lane >> 4;              // k column-group

    for (int ml = 0; ml < MLOOP; ++ml) {
        int tile = m0 + ml;
        if (tile >= Mt) return;
        const float* xp = X + (size_t)(tile * 16 + r_lo) * KD + cg * 8;

        f32x4 acc[NTS];
        #pragma unroll
        for (int i = 0; i < NTS; ++i) acc[i] = (f32x4){0.f, 0.f, 0.f, 0.f};

        float4 alo[PFA], ahi[PFA];
        #pragma unroll
        for (int i = 0; i < PFA; ++i) {
            alo[i] = *(const float4*)(xp + i * 32);
            ahi[i] = *(const float4*)(xp + i * 32 + 4);
        }

        #pragma unroll
        for (int kc = 0; kc < KC; ++kc) {
            float4 lo = alo[kc % PFA], hi = ahi[kc % PFA];
            int ka = kc + PFA; if (ka > KC - 1) ka = KC - 1;
            alo[kc % PFA] = *(const float4*)(xp + ka * 32);
            ahi[kc % PFA] = *(const float4*)(xp + ka * 32 + 4);
            bf16x8 a = cvt8(lo, hi);
            #pragma unroll
            for (int nt = 0; nt < NTS; ++nt)
                acc[nt] = __builtin_amdgcn_mfma_f32_16x16x32_bf16(a, breg[kc * NTS + nt],
                                                                  acc[nt], 0, 0, 0);
        }

        #pragma unroll
        for (int nt = 0; nt < NTS; ++nt) {
            #pragma unroll
            for (int r = 0; r < 4; ++r) {
                int grow = tile * 16 + cg * 4 + r;
                C[(size_t)grow * NC + (ws * NTS + nt) * 16 + r_lo] = f32_to_bf16(acc[nt][r]);
            }
        }
    }
}

// ---------------- fragment MFMA GEMM (A already in fragment order, bf16) ----------------

template<int NC, int KD>
__global__ __launch_bounds__(256) void mfma_gemm_frag(const bf16x8* __restrict__ Afrag,
                                                      const bf16x8* __restrict__ Bfrag,
                                                      short* __restrict__ C, int Mt) {
    constexpr int NT = NC / 16, KC = KD / 32;
    constexpr int PFA = (KC < 4) ? KC : 4;
    const int lane = threadIdx.x & 63;
    const int wave = threadIdx.x >> 6;
    const int tile = blockIdx.x * 4 + wave;
    if (tile >= Mt) return;

    const bf16x8* ap = Afrag + (size_t)tile * KC * 64 + lane;
    const bf16x8* bp = Bfrag + lane;

    f32x4 acc[NT];
    #pragma unroll
    for (int i = 0; i < NT; ++i) acc[i] = (f32x4){0.f, 0.f, 0.f, 0.f};

    bf16x8 abuf[PFA];
    #pragma unroll
    for (int i = 0; i < PFA; ++i) abuf[i] = ap[(size_t)i * 64];
    bf16x8 bbuf[NT];
    #pragma unroll
    for (int nt = 0; nt < NT; ++nt) bbuf[nt] = bp[(size_t)nt * 64];

    #pragma unroll
    for (int kc = 0; kc < KC; ++kc) {
        bf16x8 a = abuf[kc % PFA];
        int ka = kc + PFA; if (ka > KC - 1) ka = KC - 1;
        abuf[kc % PFA] = ap[(size_t)ka * 64];
        int kb = (kc + 1 < KC) ? kc + 1 : kc;
        bf16x8 bnew[NT];
        #pragma unroll
        for (int nt = 0; nt < NT; ++nt) {
            bnew[nt] = bp[((size_t)kb * NT + nt) * 64];
            acc[nt] = __builtin_amdgcn_mfma_f32_16x16x32_bf16(a, bbuf[nt], acc[nt], 0, 0, 0);
        }
        #pragma unroll
        for (int nt = 0; nt < NT; ++nt) bbuf[nt] = bnew[nt];
    }

    const int lrow = lane & 15, kgrp = lane >> 4;
    #pragma unroll
    for (int nt = 0; nt < NT; ++nt) {
        #pragma unroll
        for (int r = 0; r < 4; ++r) {
            int grow = tile * 16 + kgrp * 4 + r;
            C[(size_t)grow * NC + nt * 16 + lrow] = f32_to_bf16(acc[nt][r]);
        }
    }
}

// ---------------- SpMM gather ----------------

// F=128: one wave per node. 8-wide UNMASKED main loop, software-pipelined:
// erec batch for iteration i+1 issues while iteration i's feat gathers are in
// flight. Tails: 4-wide then scalar (no per-edge compares anywhere).
__global__ __launch_bounds__(64) void spmm128(const int2* __restrict__ rowinfo,
                                              const uint2* __restrict__ erec,
                                              const unsigned* __restrict__ featu,
                                              const float* __restrict__ bias,
                                              float* __restrict__ out,
                                              unsigned* __restrict__ afrag2u) {
    int d = blockIdx.x, tid = threadIdx.x;
    int2 ri = rowinfo[d];
    int beg = ri.x, end = ri.y;
    float a0 = 0.f, a1 = 0.f;
    const unsigned* fp = featu + tid;
    int e = beg;
    if (end - beg >= 8) {
        uint2 r[8];
        #pragma unroll
        for (int j = 0; j < 8; ++j) r[j] = erec[e + j];
        for (; e + 16 <= end; e += 8) {
            unsigned f[8];
            #pragma unroll
            for (int j = 0; j < 8; ++j) f[j] = fp[r[j].x * 64u];
            uint2 rn[8];
            #pragma unroll
            for (int j = 0; j < 8; ++j) rn[j] = erec[e + 8 + j];
            #pragma unroll
            for (int j = 0; j < 8; ++j) {
                float w = __uint_as_float(r[j].y);
                a0 += w * bf16lo(f[j]);
                a1 += w * bf16hi(f[j]);
            }
            #pragma unroll
            for (int j = 0; j < 8; ++j) r[j] = rn[j];
        }
        {   // drain: last full batch, no prefetch
            unsigned f[8];
            #pragma unroll
            for (int j = 0; j < 8; ++j) f[j] = fp[r[j].x * 64u];
            #pragma unroll
            for (int j = 0; j < 8; ++j) {
                float w = __uint_as_float(r[j].y);
                a0 += w * bf16lo(f[j]);
                a1 += w * bf16hi(f[j]);
            }
            e += 8;
        }
    }
    for (; e + 4 <= end; e += 4) {
        uint2 r0 = erec[e], r1 = erec[e + 1], r2 = erec[e + 2], r3 = erec[e + 3];
        unsigned f0 = fp[r0.x * 64u];
        unsigned f1 = fp[r1.x * 64u];
        unsigned f2 = fp[r2.x * 64u];
        unsigned f3 = fp[r3.x * 64u];
        float w0 = __uint_as_float(r0.y), w1 = __uint_as_float(r1.y);
        float w2 = __uint_as_float(r2.y), w3 = __uint_as_float(r3.y);
        a0 += w0 * bf16lo(f0); a1 += w0 * bf16hi(f0);
        a0 += w1 * bf16lo(f1); a1 += w1 * bf16hi(f1);
        a0 += w2 * bf16lo(f2); a1 += w2 * bf16hi(f2);
        a0 += w3 * bf16lo(f3); a1 += w3 * bf16hi(f3);
    }
    for (; e < end; ++e) {
        uint2 r = erec[e];
        unsigned f = fp[r.x * 64u];
        float w = __uint_as_float(r.y);
        a0 += w * bf16lo(f); a1 += w * bf16hi(f);
    }
    float ox = fmaxf(a0 + bias[2 * tid], 0.f);
    float oy = fmaxf(a1 + bias[2 * tid + 1], 0.f);
    *(float2*)&out[(size_t)d * 128 + 2 * tid] = make_float2(ox, oy);
    unsigned packed = (unsigned)(unsigned short)f32_to_bf16(ox) |
                      ((unsigned)(unsigned short)f32_to_bf16(oy) << 16);
    int unit = ((d >> 4) * 4 + (tid >> 4)) * 64 + ((tid >> 2) & 3) * 16 + (d & 15);
    afrag2u[unit * 4 + (tid & 3)] = packed;
}

// F=64: one wave per node, same pipelined 8-wide structure.
__global__ __launch_bounds__(64) void spmm64(const int2* __restrict__ rowinfo,
                                             const uint2* __restrict__ erec,
                                             const short* __restrict__ feat,
                                             const float* __restrict__ bias,
                                             float* __restrict__ out) {
    int d = blockIdx.x, tid = threadIdx.x;
    int2 ri = rowinfo[d];
    int beg = ri.x, end = ri.y;
    float acc = 0.f;
    const short* fp = feat + tid;
    int e = beg;
    if (end - beg >= 8) {
        uint2 r[8];
        #pragma unroll
        for (int j = 0; j < 8; ++j) r[j] = erec[e + j];
        for (; e + 16 <= end; e += 8) {
            float f[8];
            #pragma unroll
            for (int j = 0; j < 8; ++j) f[j] = bf16_to_f32(fp[r[j].x * 64u]);
            uint2 rn[8];
            #pragma unroll
            for (int j = 0; j < 8; ++j) rn[j] = erec[e + 8 + j];
            #pragma unroll
            for (int j = 0; j < 8; ++j) acc += __uint_as_float(r[j].y) * f[j];
            #pragma unroll
            for (int j = 0; j < 8; ++j) r[j] = rn[j];
        }
        {
            float f[8];
            #pragma unroll
            for (int j = 0; j < 8; ++j) f[j] = bf16_to_f32(fp[r[j].x * 64u]);
            #pragma unroll
            for (int j = 0; j < 8; ++j) acc += __uint_as_float(r[j].y) * f[j];
            e += 8;
        }
    }
    for (; e + 4 <= end; e += 4) {
        uint2 r0 = erec[e], r1 = erec[e + 1], r2 = erec[e + 2], r3 = erec[e + 3];
        float f0 = bf16_to_f32(fp[r0.x * 64u]);
        float f1 = bf16_to_f32(fp[r1.x * 64u]);
        float f2 = bf16_to_f32(fp[r2.x * 64u]);
        float f3 = bf16_to_f32(fp[r3.x * 64u]);
        acc += __uint_as_float(r0.y) * f0;
        acc += __uint_as_float(r1.y) * f1;
        acc += __uint_as_float(r2.y) * f2;
        acc += __uint_as_float(r3.y) * f3;
    }
    for (; e < end; ++e) {
        uint2 r = erec[e];
        acc += __uint_as_float(r.y) * bf16_to_f32(fp[r.x * 64u]);
    }
    out[(size_t)d * 64 + tid] = acc + bias[tid];
}

// ---------------- launch ----------------

extern "C" void kernel_launch(void* const* d_in, const int* in_sizes, int n_in,
                              void* d_out, int out_size, void* d_ws, size_t ws_size,
                              hipStream_t stream) {
    const float* x  = (const float*)d_in[0];
    const int*   ei = (const int*)d_in[1];
    const float* ew = (const float*)d_in[2];
    const float* W1 = (const float*)d_in[3];
    const float* b1 = (const float*)d_in[4];
    const float* W2 = (const float*)d_in[5];
    const float* b2 = (const float*)d_in[6];

    const int* dst = ei;
    const int* src = ei + N_EDGES;

    float* x1 = (float*)d_out;                          // [50000,128] fp32
    float* x2 = x1 + (size_t)N_NODES * F_HID;           // [50000,64]  fp32

    char* ws = (char*)d_ws;
    uint2*  erec     = (uint2*)ws;  ws += (size_t)NBUK * CAP * 8;         // 15.2 MB (slotted)
    uint2*  tmp      = (uint2*)ws;  ws += (size_t)NBUK * CAP * 8;         // 15.2 MB (slotted)
    short*  support1 = (short*)ws;  ws += (size_t)N_NODES * F_HID * 2;    // 12.8 MB
    short*  support2 = (short*)ws;  ws += (size_t)N_NODES * F_OUT * 2;    //  6.4 MB
    bf16x8* Afrag2   = (bf16x8*)ws; ws += (size_t)N_NODES * F_HID * 2;    // 12.8 MB
    bf16x8* Bfrag1   = (bf16x8*)ws; ws += (size_t)F_HID * F_IN * 2;       //  128 KB
    bf16x8* Bfrag2   = (bf16x8*)ws; ws += (size_t)F_OUT * F_HID * 2;      //   16 KB
    int2*   rowinfo  = (int2*)ws;   ws += (size_t)N_NODES * 8;            //  400 KB
    int*    gcnt     = (int*)ws;    ws += 400 * 4;

    const int NPB = (N_EDGES + EPB - 1) / EPB;          // 196 partition blocks
    const int MT  = N_NODES / 16;                       // 3125 row tiles (exact)

    // 1) CSR build (bucket partition, self-reserving fixed-capacity slots)
    hipMemsetAsync(gcnt, 0, NBUK * sizeof(int), stream);
    part_a<<<NPB, 256, 0, stream>>>(dst, src, ew, gcnt, tmp, N_EDGES);
    part_b<<<NBUK, 256, 0, stream>>>(tmp, gcnt, rowinfo, erec);

    // 2) weight prep (fragment-order bf16)
    wtrans_frag<F_IN, F_HID><<<32, 256, 0, stream>>>(W1, Bfrag1);
    wtrans_frag<F_HID, F_OUT><<<4, 256, 0, stream>>>(W2, Bfrag2);

    // 3) support1 = x @ W1 (bf16 out) — B-slice in registers, MLOOP=4 m-tiles/wave
    {
        constexpr int MLOOP = 4;
        int blocks = (MT + MLOOP - 1) / MLOOP;          // 782 (MW=1: 4 waves share m-range)
        mfma_gemm_xr<F_HID, F_IN, 2, MLOOP><<<blocks, 256, 0, stream>>>(x, Bfrag1, support1, MT);
    }

    // 4) x1 = relu(spmm(support1) + b1); also emits Afrag2 (bf16 fragment order)
    spmm128<<<N_NODES, 64, 0, stream>>>(rowinfo, erec, (const unsigned*)support1, b1, x1,
                                        (unsigned*)Afrag2);

    // 5) support2 = x1 @ W2 (bf16 out)
    mfma_gemm_frag<F_OUT, F_HID><<<(MT + 3) / 4, 256, 0, stream>>>(Afrag2, Bfrag2, support2, MT);

    // 6) x2 = spmm(support2) + b2
    spmm64<<<N_NODES, 64, 0, stream>>>(rowinfo, erec, support2, b2, x2);
}

// Round 7
// 352.968 us; speedup vs baseline: 1.0774x; 1.0774x over previous
//
#include <hip/hip_runtime.h>
#include <hip/hip_bf16.h>

#define N_NODES 50000
#define N_EDGES 1600000
#define F_IN    512
#define F_HID   128
#define F_OUT   64
#define NBUK    391          // ceil(50000/128) buckets of 128 nodes
#define EPB     8192         // edges per block in bucket passes
#define CAP     4864         // per-bucket slot capacity (mean 4092, +12 sigma)

typedef short bf16x8 __attribute__((ext_vector_type(8)));
typedef float f32x4  __attribute__((ext_vector_type(4)));

__device__ __forceinline__ short f32_to_bf16(float f) {
    unsigned u = __float_as_uint(f);
    u += 0x7FFF + ((u >> 16) & 1);          // RTNE
    return (short)(u >> 16);
}
__device__ __forceinline__ float bf16_to_f32(short s) {
    return __uint_as_float(((unsigned)(unsigned short)s) << 16);
}
__device__ __forceinline__ float bf16lo(unsigned u) { return __uint_as_float(u << 16); }
__device__ __forceinline__ float bf16hi(unsigned u) { return __uint_as_float(u & 0xFFFF0000u); }

// 8x f32 -> bf16x8 via packed HW convert (RNE); 4 instrs instead of 24.
__device__ __forceinline__ bf16x8 cvt8(float4 lo, float4 hi) {
    union { unsigned u[4]; bf16x8 v; } r;
    asm("v_cvt_pk_bf16_f32 %0, %1, %2" : "=v"(r.u[0]) : "v"(lo.x), "v"(lo.y));
    asm("v_cvt_pk_bf16_f32 %0, %1, %2" : "=v"(r.u[1]) : "v"(lo.z), "v"(lo.w));
    asm("v_cvt_pk_bf16_f32 %0, %1, %2" : "=v"(r.u[2]) : "v"(hi.x), "v"(hi.y));
    asm("v_cvt_pk_bf16_f32 %0, %1, %2" : "=v"(r.u[3]) : "v"(hi.z), "v"(hi.w));
    return r.v;
}

// ---------------- CSR build: bucket partition with fixed-capacity slots ----------------

__global__ __launch_bounds__(256) void part_a(const int* __restrict__ dst,
                                              const int* __restrict__ src,
                                              const float* __restrict__ w,
                                              int* __restrict__ gcnt,
                                              uint2* __restrict__ tmp, int E) {
    __shared__ int h[NBUK];
    __shared__ int base[NBUK];
    for (int i = threadIdx.x; i < NBUK; i += 256) h[i] = 0;
    __syncthreads();
    int e0 = blockIdx.x * EPB;
    int e1 = min(e0 + EPB, E);
    for (int e = e0 + threadIdx.x; e < e1; e += 256)
        atomicAdd(&h[dst[e] >> 7], 1);
    __syncthreads();
    for (int i = threadIdx.x; i < NBUK; i += 256) {
        int c = h[i];
        base[i] = c ? atomicAdd(&gcnt[i], c) : 0;
        h[i] = 0;
    }
    __syncthreads();
    for (int e = e0 + threadIdx.x; e < e1; e += 256) {
        int d = dst[e];
        int b = d >> 7;
        int off = base[b] + atomicAdd(&h[b], 1);
        if (off < CAP)
            tmp[(size_t)b * CAP + off] = make_uint2(((unsigned)d << 16) | (unsigned)src[e],
                                                    __float_as_uint(w[e]));
    }
}

__global__ __launch_bounds__(256) void part_b(const uint2* __restrict__ tmp,
                                              const int* __restrict__ gcnt,
                                              int2* __restrict__ rowinfo,
                                              uint2* __restrict__ erec) {
    __shared__ int s[128];
    __shared__ int cur[128];
    int b = blockIdx.x, tid = threadIdx.x;
    int nb0 = b << 7;
    int r0 = b * CAP;
    int cnt_b = min(gcnt[b], CAP);
    int r1 = r0 + cnt_b;
    if (tid < 128) s[tid] = 0;
    __syncthreads();
    for (int i = r0 + tid; i < r1; i += 256)
        atomicAdd(&s[(tmp[i].x >> 16) - nb0], 1);
    __syncthreads();
    int v = (tid < 128) ? s[tid] : 0;
    #pragma unroll
    for (int off = 1; off < 128; off <<= 1) {
        int t = (tid >= off && tid < 128) ? s[tid - off] : 0;
        __syncthreads();
        if (tid < 128) s[tid] += t;
        __syncthreads();
    }
    if (tid < 128) {
        int ex = r0 + s[tid] - v;
        cur[tid] = ex;
        int node = nb0 + tid;
        if (node < N_NODES) rowinfo[node] = make_int2(ex, ex + v);
    }
    __syncthreads();
    for (int i = r0 + tid; i < r1; i += 256) {
        uint2 rec = tmp[i];
        int p = atomicAdd(&cur[(rec.x >> 16) - nb0], 1);
        erec[p] = make_uint2(rec.x & 0xFFFFu, rec.y);
    }
}

// ---------------- fragment-order conversions ----------------

// B fragment unit u = (kc*NT + nt)*64 + lane:
//   holds W[k = kc*32 + (lane>>4)*8 + j][n = nt*16 + (lane&15)]  (W is [KD][NC] row-major)
template<int KD, int NC>
__global__ void wtrans_frag(const float* __restrict__ W, bf16x8* __restrict__ Bfrag) {
    constexpr int KC = KD / 32, NT = NC / 16;
    int u = blockIdx.x * 256 + threadIdx.x;
    if (u >= KC * NT * 64) return;
    int lane = u & 63;
    int nt   = (u >> 6) % NT;
    int kc   = u / (64 * NT);
    int n = nt * 16 + (lane & 15);
    int k = kc * 32 + (lane >> 4) * 8;
    bf16x8 f;
    #pragma unroll
    for (int j = 0; j < 8; ++j) f[j] = f32_to_bf16(W[(size_t)(k + j) * NC + n]);
    Bfrag[u] = f;
}

// ------------- GEMM1: LDS-staged double-buffered (64x128 tile, BK=32) -------------
// 4 waves; wave (wm,wn) computes a 32x64 quadrant. Per K-step:
//  - reg-stage (T14): 4 float4 global loads issued BEFORE compute, ds_write after
//    the post-compute barrier -> HBM latency hides under MFMA; 16 KB/block in flight.
//  - B staged once per block per step (L2 traffic 782*128KB = 100 MB, 16x less
//    than per-wave reload); A stored fragment-packed so ALL LDS reads/writes are
//    lane*16-contiguous (conflict-free).
template<int KD /*512*/, int NC /*128*/>
__global__ __launch_bounds__(256) void mfma_gemm_s1(const float* __restrict__ X,
                                                    const bf16x8* __restrict__ Bfrag,
                                                    short* __restrict__ C, int Mrows) {
    constexpr int S = KD / 32;            // 16 K-steps
    __shared__ char lds[2][16384];        // per buf: A 8KB | B 8KB
    const int tid  = threadIdx.x;
    const int lane = tid & 63;
    const int wave = tid >> 6;
    const int wm = wave >> 1, wn = wave & 1;
    const int B0 = blockIdx.x * 64;
    const int r_lo = lane & 15, cg = lane >> 4;

    // staging source pointers (thread-invariant parts)
    int rowA = B0 + wave * 16 + r_lo;
    if (rowA > Mrows - 1) rowA = Mrows - 1;          // clamp (garbage rows skipped on store)
    const char* gA = (const char*)(X + (size_t)rowA * KD) + cg * 32;   // +i*16 +s*128
    const char* gB = (const char*)Bfrag + (size_t)(wave * 2) * 1024 + (size_t)lane * 16; // +i*1024 +s*8192

    // LDS byte offsets for this thread's staging writes (A fragment-packed: chunk=(i*256+wave*64+lane))
    const int ldsA0 = (0 * 256 + wave * 64 + lane) * 16;
    const int ldsA1 = (1 * 256 + wave * 64 + lane) * 16;
    const int ldsB0 = 8192 + (wave * 2 + 0) * 1024 + lane * 16;
    const int ldsB1 = 8192 + (wave * 2 + 1) * 1024 + lane * 16;

    f32x4 acc[2][4];
    #pragma unroll
    for (int m = 0; m < 2; ++m)
        #pragma unroll
        for (int n = 0; n < 4; ++n) acc[m][n] = (f32x4){0.f, 0.f, 0.f, 0.f};

    // prologue: stage step 0 into buf 0
    float4 ra0 = *(const float4*)(gA);
    float4 ra1 = *(const float4*)(gA + 16);
    float4 rb0 = *(const float4*)(gB);
    float4 rb1 = *(const float4*)(gB + 1024);
    *(float4*)(&lds[0][ldsA0]) = ra0;
    *(float4*)(&lds[0][ldsA1]) = ra1;
    *(float4*)(&lds[0][ldsB0]) = rb0;
    *(float4*)(&lds[0][ldsB1]) = rb1;
    __syncthreads();

    int buf = 0;
    for (int s = 0; s < S; ++s) {
        if (s + 1 < S) {                              // issue next-step loads early (T14)
            size_t oa = (size_t)(s + 1) * 128;
            size_t ob = (size_t)(s + 1) * 8192;
            ra0 = *(const float4*)(gA + oa);
            ra1 = *(const float4*)(gA + 16 + oa);
            rb0 = *(const float4*)(gB + ob);
            rb1 = *(const float4*)(gB + 1024 + ob);
        }
        const char* A_ = lds[buf];
        const char* B_ = lds[buf] + 8192;
        bf16x8 bb[4];
        #pragma unroll
        for (int n = 0; n < 4; ++n)
            bb[n] = *(const bf16x8*)(B_ + (wn * 4 + n) * 1024 + lane * 16);
        #pragma unroll
        for (int m = 0; m < 2; ++m) {
            int t = wm * 2 + m;
            float4 lo = *(const float4*)(A_ + (0 * 256 + t * 64 + lane) * 16);
            float4 hi = *(const float4*)(A_ + (1 * 256 + t * 64 + lane) * 16);
            bf16x8 a = cvt8(lo, hi);
            #pragma unroll
            for (int n = 0; n < 4; ++n)
                acc[m][n] = __builtin_amdgcn_mfma_f32_16x16x32_bf16(a, bb[n], acc[m][n], 0, 0, 0);
        }
        if (s + 1 < S) {
            __syncthreads();                          // everyone done reading buf^1 (prev step)
            char* An = lds[buf ^ 1];
            *(float4*)(&An[ldsA0]) = ra0;
            *(float4*)(&An[ldsA1]) = ra1;
            *(float4*)(&An[ldsB0]) = rb0;
            *(float4*)(&An[ldsB1]) = rb1;
            __syncthreads();                          // writes visible for next compute
            buf ^= 1;
        }
    }

    #pragma unroll
    for (int m = 0; m < 2; ++m) {
        int tile16 = (B0 >> 4) + wm * 2 + m;
        if (tile16 * 16 < Mrows) {
            #pragma unroll
            for (int n = 0; n < 4; ++n) {
                #pragma unroll
                for (int r = 0; r < 4; ++r) {
                    int grow = tile16 * 16 + cg * 4 + r;
                    C[(size_t)grow * NC + (wn * 4 + n) * 16 + r_lo] = f32_to_bf16(acc[m][n][r]);
                }
            }
        }
    }
}

// ---------------- fragment MFMA GEMM (A already in fragment order, bf16) ----------------

template<int NC, int KD>
__global__ __launch_bounds__(256) void mfma_gemm_frag(const bf16x8* __restrict__ Afrag,
                                                      const bf16x8* __restrict__ Bfrag,
                                                      short* __restrict__ C, int Mt) {
    constexpr int NT = NC / 16, KC = KD / 32;
    constexpr int PFA = (KC < 4) ? KC : 4;
    const int lane = threadIdx.x & 63;
    const int wave = threadIdx.x >> 6;
    const int tile = blockIdx.x * 4 + wave;
    if (tile >= Mt) return;

    const bf16x8* ap = Afrag + (size_t)tile * KC * 64 + lane;
    const bf16x8* bp = Bfrag + lane;

    f32x4 acc[NT];
    #pragma unroll
    for (int i = 0; i < NT; ++i) acc[i] = (f32x4){0.f, 0.f, 0.f, 0.f};

    bf16x8 abuf[PFA];
    #pragma unroll
    for (int i = 0; i < PFA; ++i) abuf[i] = ap[(size_t)i * 64];
    bf16x8 bbuf[NT];
    #pragma unroll
    for (int nt = 0; nt < NT; ++nt) bbuf[nt] = bp[(size_t)nt * 64];

    #pragma unroll
    for (int kc = 0; kc < KC; ++kc) {
        bf16x8 a = abuf[kc % PFA];
        int ka = kc + PFA; if (ka > KC - 1) ka = KC - 1;
        abuf[kc % PFA] = ap[(size_t)ka * 64];
        int kb = (kc + 1 < KC) ? kc + 1 : kc;
        bf16x8 bnew[NT];
        #pragma unroll
        for (int nt = 0; nt < NT; ++nt) {
            bnew[nt] = bp[((size_t)kb * NT + nt) * 64];
            acc[nt] = __builtin_amdgcn_mfma_f32_16x16x32_bf16(a, bbuf[nt], acc[nt], 0, 0, 0);
        }
        #pragma unroll
        for (int nt = 0; nt < NT; ++nt) bbuf[nt] = bnew[nt];
    }

    const int lrow = lane & 15, kgrp = lane >> 4;
    #pragma unroll
    for (int nt = 0; nt < NT; ++nt) {
        #pragma unroll
        for (int r = 0; r < 4; ++r) {
            int grow = tile * 16 + kgrp * 4 + r;
            C[(size_t)grow * NC + nt * 16 + lrow] = f32_to_bf16(acc[nt][r]);
        }
    }
}

// ---------------- SpMM gather ----------------

// F=128: one wave per node. 8-wide UNMASKED main loop, software-pipelined:
// erec batch for iteration i+1 issues while iteration i's feat gathers are in
// flight. Tails: 4-wide then scalar (no per-edge compares anywhere).
__global__ __launch_bounds__(64) void spmm128(const int2* __restrict__ rowinfo,
                                              const uint2* __restrict__ erec,
                                              const unsigned* __restrict__ featu,
                                              const float* __restrict__ bias,
                                              float* __restrict__ out,
                                              unsigned* __restrict__ afrag2u) {
    int d = blockIdx.x, tid = threadIdx.x;
    int2 ri = rowinfo[d];
    int beg = ri.x, end = ri.y;
    float a0 = 0.f, a1 = 0.f;
    const unsigned* fp = featu + tid;
    int e = beg;
    if (end - beg >= 8) {
        uint2 r[8];
        #pragma unroll
        for (int j = 0; j < 8; ++j) r[j] = erec[e + j];
        for (; e + 16 <= end; e += 8) {
            unsigned f[8];
            #pragma unroll
            for (int j = 0; j < 8; ++j) f[j] = fp[r[j].x * 64u];
            uint2 rn[8];
            #pragma unroll
            for (int j = 0; j < 8; ++j) rn[j] = erec[e + 8 + j];
            #pragma unroll
            for (int j = 0; j < 8; ++j) {
                float w = __uint_as_float(r[j].y);
                a0 += w * bf16lo(f[j]);
                a1 += w * bf16hi(f[j]);
            }
            #pragma unroll
            for (int j = 0; j < 8; ++j) r[j] = rn[j];
        }
        {   // drain: last full batch, no prefetch
            unsigned f[8];
            #pragma unroll
            for (int j = 0; j < 8; ++j) f[j] = fp[r[j].x * 64u];
            #pragma unroll
            for (int j = 0; j < 8; ++j) {
                float w = __uint_as_float(r[j].y);
                a0 += w * bf16lo(f[j]);
                a1 += w * bf16hi(f[j]);
            }
            e += 8;
        }
    }
    for (; e + 4 <= end; e += 4) {
        uint2 r0 = erec[e], r1 = erec[e + 1], r2 = erec[e + 2], r3 = erec[e + 3];
        unsigned f0 = fp[r0.x * 64u];
        unsigned f1 = fp[r1.x * 64u];
        unsigned f2 = fp[r2.x * 64u];
        unsigned f3 = fp[r3.x * 64u];
        float w0 = __uint_as_float(r0.y), w1 = __uint_as_float(r1.y);
        float w2 = __uint_as_float(r2.y), w3 = __uint_as_float(r3.y);
        a0 += w0 * bf16lo(f0); a1 += w0 * bf16hi(f0);
        a0 += w1 * bf16lo(f1); a1 += w1 * bf16hi(f1);
        a0 += w2 * bf16lo(f2); a1 += w2 * bf16hi(f2);
        a0 += w3 * bf16lo(f3); a1 += w3 * bf16hi(f3);
    }
    for (; e < end; ++e) {
        uint2 r = erec[e];
        unsigned f = fp[r.x * 64u];
        float w = __uint_as_float(r.y);
        a0 += w * bf16lo(f); a1 += w * bf16hi(f);
    }
    float ox = fmaxf(a0 + bias[2 * tid], 0.f);
    float oy = fmaxf(a1 + bias[2 * tid + 1], 0.f);
    *(float2*)&out[(size_t)d * 128 + 2 * tid] = make_float2(ox, oy);
    unsigned packed = (unsigned)(unsigned short)f32_to_bf16(ox) |
                      ((unsigned)(unsigned short)f32_to_bf16(oy) << 16);
    int unit = ((d >> 4) * 4 + (tid >> 4)) * 64 + ((tid >> 2) & 3) * 16 + (d & 15);
    afrag2u[unit * 4 + (tid & 3)] = packed;
}

// F=64: one wave per node, same pipelined 8-wide structure.
__global__ __launch_bounds__(64) void spmm64(const int2* __restrict__ rowinfo,
                                             const uint2* __restrict__ erec,
                                             const short* __restrict__ feat,
                                             const float* __restrict__ bias,
                                             float* __restrict__ out) {
    int d = blockIdx.x, tid = threadIdx.x;
    int2 ri = rowinfo[d];
    int beg = ri.x, end = ri.y;
    float acc = 0.f;
    const short* fp = feat + tid;
    int e = beg;
    if (end - beg >= 8) {
        uint2 r[8];
        #pragma unroll
        for (int j = 0; j < 8; ++j) r[j] = erec[e + j];
        for (; e + 16 <= end; e += 8) {
            float f[8];
            #pragma unroll
            for (int j = 0; j < 8; ++j) f[j] = bf16_to_f32(fp[r[j].x * 64u]);
            uint2 rn[8];
            #pragma unroll
            for (int j = 0; j < 8; ++j) rn[j] = erec[e + 8 + j];
            #pragma unroll
            for (int j = 0; j < 8; ++j) acc += __uint_as_float(r[j].y) * f[j];
            #pragma unroll
            for (int j = 0; j < 8; ++j) r[j] = rn[j];
        }
        {
            float f[8];
            #pragma unroll
            for (int j = 0; j < 8; ++j) f[j] = bf16_to_f32(fp[r[j].x * 64u]);
            #pragma unroll
            for (int j = 0; j < 8; ++j) acc += __uint_as_float(r[j].y) * f[j];
            e += 8;
        }
    }
    for (; e + 4 <= end; e += 4) {
        uint2 r0 = erec[e], r1 = erec[e + 1], r2 = erec[e + 2], r3 = erec[e + 3];
        float f0 = bf16_to_f32(fp[r0.x * 64u]);
        float f1 = bf16_to_f32(fp[r1.x * 64u]);
        float f2 = bf16_to_f32(fp[r2.x * 64u]);
        float f3 = bf16_to_f32(fp[r3.x * 64u]);
        acc += __uint_as_float(r0.y) * f0;
        acc += __uint_as_float(r1.y) * f1;
        acc += __uint_as_float(r2.y) * f2;
        acc += __uint_as_float(r3.y) * f3;
    }
    for (; e < end; ++e) {
        uint2 r = erec[e];
        acc += __uint_as_float(r.y) * bf16_to_f32(fp[r.x * 64u]);
    }
    out[(size_t)d * 64 + tid] = acc + bias[tid];
}

// ---------------- launch ----------------

extern "C" void kernel_launch(void* const* d_in, const int* in_sizes, int n_in,
                              void* d_out, int out_size, void* d_ws, size_t ws_size,
                              hipStream_t stream) {
    const float* x  = (const float*)d_in[0];
    const int*   ei = (const int*)d_in[1];
    const float* ew = (const float*)d_in[2];
    const float* W1 = (const float*)d_in[3];
    const float* b1 = (const float*)d_in[4];
    const float* W2 = (const float*)d_in[5];
    const float* b2 = (const float*)d_in[6];

    const int* dst = ei;
    const int* src = ei + N_EDGES;

    float* x1 = (float*)d_out;                          // [50000,128] fp32
    float* x2 = x1 + (size_t)N_NODES * F_HID;           // [50000,64]  fp32

    char* ws = (char*)d_ws;
    uint2*  erec     = (uint2*)ws;  ws += (size_t)NBUK * CAP * 8;         // 15.2 MB (slotted)
    uint2*  tmp      = (uint2*)ws;  ws += (size_t)NBUK * CAP * 8;         // 15.2 MB (slotted)
    short*  support1 = (short*)ws;  ws += (size_t)N_NODES * F_HID * 2;    // 12.8 MB
    short*  support2 = (short*)ws;  ws += (size_t)N_NODES * F_OUT * 2;    //  6.4 MB
    bf16x8* Afrag2   = (bf16x8*)ws; ws += (size_t)N_NODES * F_HID * 2;    // 12.8 MB
    bf16x8* Bfrag1   = (bf16x8*)ws; ws += (size_t)F_HID * F_IN * 2;       //  128 KB
    bf16x8* Bfrag2   = (bf16x8*)ws; ws += (size_t)F_OUT * F_HID * 2;      //   16 KB
    int2*   rowinfo  = (int2*)ws;   ws += (size_t)N_NODES * 8;            //  400 KB
    int*    gcnt     = (int*)ws;    ws += 400 * 4;

    const int NPB = (N_EDGES + EPB - 1) / EPB;          // 196 partition blocks
    const int MT  = N_NODES / 16;                       // 3125 row tiles (exact)

    // 1) CSR build (bucket partition, self-reserving fixed-capacity slots)
    hipMemsetAsync(gcnt, 0, NBUK * sizeof(int), stream);
    part_a<<<NPB, 256, 0, stream>>>(dst, src, ew, gcnt, tmp, N_EDGES);
    part_b<<<NBUK, 256, 0, stream>>>(tmp, gcnt, rowinfo, erec);

    // 2) weight prep (fragment-order bf16)
    wtrans_frag<F_IN, F_HID><<<32, 256, 0, stream>>>(W1, Bfrag1);
    wtrans_frag<F_HID, F_OUT><<<4, 256, 0, stream>>>(W2, Bfrag2);

    // 3) support1 = x @ W1 (bf16 out) — LDS-staged double-buffered GEMM
    {
        int blocks = (N_NODES + 63) / 64;               // 782
        mfma_gemm_s1<F_IN, F_HID><<<blocks, 256, 0, stream>>>(x, Bfrag1, support1, N_NODES);
    }

    // 4) x1 = relu(spmm(support1) + b1); also emits Afrag2 (bf16 fragment order)
    spmm128<<<N_NODES, 64, 0, stream>>>(rowinfo, erec, (const unsigned*)support1, b1, x1,
                                        (unsigned*)Afrag2);

    // 5) support2 = x1 @ W2 (bf16 out)
    mfma_gemm_frag<F_OUT, F_HID><<<(MT + 3) / 4, 256, 0, stream>>>(Afrag2, Bfrag2, support2, MT);

    // 6) x2 = spmm(support2) + b2
    spmm64<<<N_NODES, 64, 0, stream>>>(rowinfo, erec, support2, b2, x2);
}

// Round 8
// 350.907 us; speedup vs baseline: 1.0837x; 1.0059x over previous
//
#include <hip/hip_runtime.h>
#include <hip/hip_bf16.h>

#define N_NODES 50000
#define N_EDGES 1600000
#define F_IN    512
#define F_HID   128
#define F_OUT   64
#define NBUK    391          // ceil(50000/128) buckets of 128 nodes
#define EPB     8192         // edges per block in bucket passes
#define CAP     4864         // per-bucket slot capacity (mean 4092, +12 sigma)

typedef short bf16x8 __attribute__((ext_vector_type(8)));
typedef float f32x4  __attribute__((ext_vector_type(4)));

__device__ __forceinline__ short f32_to_bf16(float f) {
    unsigned u = __float_as_uint(f);
    u += 0x7FFF + ((u >> 16) & 1);          // RTNE
    return (short)(u >> 16);
}
__device__ __forceinline__ float bf16_to_f32(short s) {
    return __uint_as_float(((unsigned)(unsigned short)s) << 16);
}
__device__ __forceinline__ float bf16lo(unsigned u) { return __uint_as_float(u << 16); }
__device__ __forceinline__ float bf16hi(unsigned u) { return __uint_as_float(u & 0xFFFF0000u); }

// 8x f32 -> bf16x8 via packed HW convert (RNE); 4 instrs instead of 24.
__device__ __forceinline__ bf16x8 cvt8(float4 lo, float4 hi) {
    union { unsigned u[4]; bf16x8 v; } r;
    asm("v_cvt_pk_bf16_f32 %0, %1, %2" : "=v"(r.u[0]) : "v"(lo.x), "v"(lo.y));
    asm("v_cvt_pk_bf16_f32 %0, %1, %2" : "=v"(r.u[1]) : "v"(lo.z), "v"(lo.w));
    asm("v_cvt_pk_bf16_f32 %0, %1, %2" : "=v"(r.u[2]) : "v"(hi.x), "v"(hi.y));
    asm("v_cvt_pk_bf16_f32 %0, %1, %2" : "=v"(r.u[3]) : "v"(hi.z), "v"(hi.w));
    return r.v;
}

// async global->LDS, 16B per lane; LDS dest = wave-uniform base + lane*16 (HW rule)
__device__ __forceinline__ void gload16(const void* g, void* l) {
    __builtin_amdgcn_global_load_lds((const __attribute__((address_space(1))) void*)g,
                                     (__attribute__((address_space(3))) void*)l, 16, 0, 0);
}

// ---------------- CSR build: bucket partition with fixed-capacity slots ----------------

__global__ __launch_bounds__(256) void part_a(const int* __restrict__ dst,
                                              const int* __restrict__ src,
                                              const float* __restrict__ w,
                                              int* __restrict__ gcnt,
                                              uint2* __restrict__ tmp, int E) {
    __shared__ int h[NBUK];
    __shared__ int base[NBUK];
    for (int i = threadIdx.x; i < NBUK; i += 256) h[i] = 0;
    __syncthreads();
    int e0 = blockIdx.x * EPB;
    int e1 = min(e0 + EPB, E);
    for (int e = e0 + threadIdx.x; e < e1; e += 256)
        atomicAdd(&h[dst[e] >> 7], 1);
    __syncthreads();
    for (int i = threadIdx.x; i < NBUK; i += 256) {
        int c = h[i];
        base[i] = c ? atomicAdd(&gcnt[i], c) : 0;
        h[i] = 0;
    }
    __syncthreads();
    for (int e = e0 + threadIdx.x; e < e1; e += 256) {
        int d = dst[e];
        int b = d >> 7;
        int off = base[b] + atomicAdd(&h[b], 1);
        if (off < CAP)
            tmp[(size_t)b * CAP + off] = make_uint2(((unsigned)d << 16) | (unsigned)src[e],
                                                    __float_as_uint(w[e]));
    }
}

__global__ __launch_bounds__(256) void part_b(const uint2* __restrict__ tmp,
                                              const int* __restrict__ gcnt,
                                              int2* __restrict__ rowinfo,
                                              uint2* __restrict__ erec) {
    __shared__ int s[128];
    __shared__ int cur[128];
    int b = blockIdx.x, tid = threadIdx.x;
    int nb0 = b << 7;
    int r0 = b * CAP;
    int cnt_b = min(gcnt[b], CAP);
    int r1 = r0 + cnt_b;
    if (tid < 128) s[tid] = 0;
    __syncthreads();
    for (int i = r0 + tid; i < r1; i += 256)
        atomicAdd(&s[(tmp[i].x >> 16) - nb0], 1);
    __syncthreads();
    int v = (tid < 128) ? s[tid] : 0;
    #pragma unroll
    for (int off = 1; off < 128; off <<= 1) {
        int t = (tid >= off && tid < 128) ? s[tid - off] : 0;
        __syncthreads();
        if (tid < 128) s[tid] += t;
        __syncthreads();
    }
    if (tid < 128) {
        int ex = r0 + s[tid] - v;
        cur[tid] = ex;
        int node = nb0 + tid;
        if (node < N_NODES) rowinfo[node] = make_int2(ex, ex + v);
    }
    __syncthreads();
    for (int i = r0 + tid; i < r1; i += 256) {
        uint2 rec = tmp[i];
        int p = atomicAdd(&cur[(rec.x >> 16) - nb0], 1);
        erec[p] = make_uint2(rec.x & 0xFFFFu, rec.y);
    }
}

// ---------------- fragment-order conversions ----------------

// B fragment unit u = (kc*NT + nt)*64 + lane:
//   holds W[k = kc*32 + (lane>>4)*8 + j][n = nt*16 + (lane&15)]  (W is [KD][NC] row-major)
template<int KD, int NC>
__global__ void wtrans_frag(const float* __restrict__ W, bf16x8* __restrict__ Bfrag) {
    constexpr int KC = KD / 32, NT = NC / 16;
    int u = blockIdx.x * 256 + threadIdx.x;
    if (u >= KC * NT * 64) return;
    int lane = u & 63;
    int nt   = (u >> 6) % NT;
    int kc   = u / (64 * NT);
    int n = nt * 16 + (lane & 15);
    int k = kc * 32 + (lane >> 4) * 8;
    bf16x8 f;
    #pragma unroll
    for (int j = 0; j < 8; ++j) f[j] = f32_to_bf16(W[(size_t)(k + j) * NC + n]);
    Bfrag[u] = f;
}

// ------------- GEMM1: global_load_lds double-buffered (64x128 tile, BK=32) -------------
// m97-style 2-phase loop: per K-step, issue 4 async global_load_lds (direct to LDS,
// no VGPR round-trip) for the NEXT step, compute the current step from LDS, then a
// single __syncthreads() (vmcnt+lgkm drain). A stored fragment-packed: both staging
// dests and compute reads are uniform-base + lane*16 (conflict-free, gload_lds-legal).
template<int KD /*512*/, int NC /*128*/>
__global__ __launch_bounds__(256) void mfma_gemm_s1(const float* __restrict__ X,
                                                    const bf16x8* __restrict__ Bfrag,
                                                    short* __restrict__ C, int Mrows) {
    constexpr int S = KD / 32;            // 16 K-steps
    __shared__ char lds[2][16384];        // per buf: A 8KB | B 8KB
    const int tid  = threadIdx.x;
    const int lane = tid & 63;
    const int wave = tid >> 6;
    const int wm = wave >> 1, wn = wave & 1;
    const int B0 = blockIdx.x * 64;
    const int r_lo = lane & 15, cg = lane >> 4;

    // per-lane global sources (identical data placement to the verified reg-staged version)
    int rowA = B0 + wave * 16 + r_lo;
    if (rowA > Mrows - 1) rowA = Mrows - 1;          // clamp (garbage rows skipped on store)
    const char* gA = (const char*)(X + (size_t)rowA * KD) + cg * 32;   // +i*16 +s*128
    const char* gB = (const char*)Bfrag + (size_t)(wave * 2) * 1024 + (size_t)lane * 16; // +j*1024 +s*8192

    // wave-uniform LDS dest bases (HW adds lane*16)
    const int dA0 = (0 * 256 + wave * 64) * 16;
    const int dA1 = (1 * 256 + wave * 64) * 16;
    const int dB0 = 8192 + (wave * 2 + 0) * 1024;
    const int dB1 = 8192 + (wave * 2 + 1) * 1024;

    f32x4 acc[2][4];
    #pragma unroll
    for (int m = 0; m < 2; ++m)
        #pragma unroll
        for (int n = 0; n < 4; ++n) acc[m][n] = (f32x4){0.f, 0.f, 0.f, 0.f};

    // prologue: stage step 0 into buf 0
    {
        char* L = lds[0];
        gload16(gA,        L + dA0);
        gload16(gA + 16,   L + dA1);
        gload16(gB,        L + dB0);
        gload16(gB + 1024, L + dB1);
    }
    __syncthreads();

    int buf = 0;
    for (int s = 0; s < S; ++s) {
        if (s + 1 < S) {                              // async-stage next step into buf^1
            char* L = lds[buf ^ 1];
            const char* a = gA + (size_t)(s + 1) * 128;
            const char* b = gB + (size_t)(s + 1) * 8192;
            gload16(a,        L + dA0);
            gload16(a + 16,   L + dA1);
            gload16(b,        L + dB0);
            gload16(b + 1024, L + dB1);
        }
        const char* A_ = lds[buf];
        const char* B_ = lds[buf] + 8192;
        bf16x8 bb[4];
        #pragma unroll
        for (int n = 0; n < 4; ++n)
            bb[n] = *(const bf16x8*)(B_ + (wn * 4 + n) * 1024 + lane * 16);
        #pragma unroll
        for (int m = 0; m < 2; ++m) {
            int t = wm * 2 + m;
            float4 lo = *(const float4*)(A_ + (0 * 256 + t * 64 + lane) * 16);
            float4 hi = *(const float4*)(A_ + (1 * 256 + t * 64 + lane) * 16);
            bf16x8 a = cvt8(lo, hi);
            #pragma unroll
            for (int n = 0; n < 4; ++n)
                acc[m][n] = __builtin_amdgcn_mfma_f32_16x16x32_bf16(a, bb[n], acc[m][n], 0, 0, 0);
        }
        __syncthreads();                              // drains gload_lds (vmcnt) + LDS reads
        buf ^= 1;
    }

    #pragma unroll
    for (int m = 0; m < 2; ++m) {
        int tile16 = (B0 >> 4) + wm * 2 + m;
        if (tile16 * 16 < Mrows) {
            #pragma unroll
            for (int n = 0; n < 4; ++n) {
                #pragma unroll
                for (int r = 0; r < 4; ++r) {
                    int grow = tile16 * 16 + cg * 4 + r;
                    C[(size_t)grow * NC + (wn * 4 + n) * 16 + r_lo] = f32_to_bf16(acc[m][n][r]);
                }
            }
        }
    }
}

// ---------------- fragment MFMA GEMM (A already in fragment order, bf16) ----------------

template<int NC, int KD>
__global__ __launch_bounds__(256) void mfma_gemm_frag(const bf16x8* __restrict__ Afrag,
                                                      const bf16x8* __restrict__ Bfrag,
                                                      short* __restrict__ C, int Mt) {
    constexpr int NT = NC / 16, KC = KD / 32;
    constexpr int PFA = (KC < 4) ? KC : 4;
    const int lane = threadIdx.x & 63;
    const int wave = threadIdx.x >> 6;
    const int tile = blockIdx.x * 4 + wave;
    if (tile >= Mt) return;

    const bf16x8* ap = Afrag + (size_t)tile * KC * 64 + lane;
    const bf16x8* bp = Bfrag + lane;

    f32x4 acc[NT];
    #pragma unroll
    for (int i = 0; i < NT; ++i) acc[i] = (f32x4){0.f, 0.f, 0.f, 0.f};

    bf16x8 abuf[PFA];
    #pragma unroll
    for (int i = 0; i < PFA; ++i) abuf[i] = ap[(size_t)i * 64];
    bf16x8 bbuf[NT];
    #pragma unroll
    for (int nt = 0; nt < NT; ++nt) bbuf[nt] = bp[(size_t)nt * 64];

    #pragma unroll
    for (int kc = 0; kc < KC; ++kc) {
        bf16x8 a = abuf[kc % PFA];
        int ka = kc + PFA; if (ka > KC - 1) ka = KC - 1;
        abuf[kc % PFA] = ap[(size_t)ka * 64];
        int kb = (kc + 1 < KC) ? kc + 1 : kc;
        bf16x8 bnew[NT];
        #pragma unroll
        for (int nt = 0; nt < NT; ++nt) {
            bnew[nt] = bp[((size_t)kb * NT + nt) * 64];
            acc[nt] = __builtin_amdgcn_mfma_f32_16x16x32_bf16(a, bbuf[nt], acc[nt], 0, 0, 0);
        }
        #pragma unroll
        for (int nt = 0; nt < NT; ++nt) bbuf[nt] = bnew[nt];
    }

    const int lrow = lane & 15, kgrp = lane >> 4;
    #pragma unroll
    for (int nt = 0; nt < NT; ++nt) {
        #pragma unroll
        for (int r = 0; r < 4; ++r) {
            int grow = tile * 16 + kgrp * 4 + r;
            C[(size_t)grow * NC + nt * 16 + lrow] = f32_to_bf16(acc[nt][r]);
        }
    }
}

// ---------------- SpMM gather ----------------

// F=128: one wave per node. 8-wide UNMASKED main loop, software-pipelined:
// erec batch for iteration i+1 issues while iteration i's feat gathers are in
// flight. Tails: 4-wide then scalar (no per-edge compares anywhere).
__global__ __launch_bounds__(64) void spmm128(const int2* __restrict__ rowinfo,
                                              const uint2* __restrict__ erec,
                                              const unsigned* __restrict__ featu,
                                              const float* __restrict__ bias,
                                              float* __restrict__ out,
                                              unsigned* __restrict__ afrag2u) {
    int d = blockIdx.x, tid = threadIdx.x;
    int2 ri = rowinfo[d];
    int beg = ri.x, end = ri.y;
    float a0 = 0.f, a1 = 0.f;
    const unsigned* fp = featu + tid;
    int e = beg;
    if (end - beg >= 8) {
        uint2 r[8];
        #pragma unroll
        for (int j = 0; j < 8; ++j) r[j] = erec[e + j];
        for (; e + 16 <= end; e += 8) {
            unsigned f[8];
            #pragma unroll
            for (int j = 0; j < 8; ++j) f[j] = fp[r[j].x * 64u];
            uint2 rn[8];
            #pragma unroll
            for (int j = 0; j < 8; ++j) rn[j] = erec[e + 8 + j];
            #pragma unroll
            for (int j = 0; j < 8; ++j) {
                float w = __uint_as_float(r[j].y);
                a0 += w * bf16lo(f[j]);
                a1 += w * bf16hi(f[j]);
            }
            #pragma unroll
            for (int j = 0; j < 8; ++j) r[j] = rn[j];
        }
        {   // drain: last full batch, no prefetch
            unsigned f[8];
            #pragma unroll
            for (int j = 0; j < 8; ++j) f[j] = fp[r[j].x * 64u];
            #pragma unroll
            for (int j = 0; j < 8; ++j) {
                float w = __uint_as_float(r[j].y);
                a0 += w * bf16lo(f[j]);
                a1 += w * bf16hi(f[j]);
            }
            e += 8;
        }
    }
    for (; e + 4 <= end; e += 4) {
        uint2 r0 = erec[e], r1 = erec[e + 1], r2 = erec[e + 2], r3 = erec[e + 3];
        unsigned f0 = fp[r0.x * 64u];
        unsigned f1 = fp[r1.x * 64u];
        unsigned f2 = fp[r2.x * 64u];
        unsigned f3 = fp[r3.x * 64u];
        float w0 = __uint_as_float(r0.y), w1 = __uint_as_float(r1.y);
        float w2 = __uint_as_float(r2.y), w3 = __uint_as_float(r3.y);
        a0 += w0 * bf16lo(f0); a1 += w0 * bf16hi(f0);
        a0 += w1 * bf16lo(f1); a1 += w1 * bf16hi(f1);
        a0 += w2 * bf16lo(f2); a1 += w2 * bf16hi(f2);
        a0 += w3 * bf16lo(f3); a1 += w3 * bf16hi(f3);
    }
    for (; e < end; ++e) {
        uint2 r = erec[e];
        unsigned f = fp[r.x * 64u];
        float w = __uint_as_float(r.y);
        a0 += w * bf16lo(f); a1 += w * bf16hi(f);
    }
    float ox = fmaxf(a0 + bias[2 * tid], 0.f);
    float oy = fmaxf(a1 + bias[2 * tid + 1], 0.f);
    *(float2*)&out[(size_t)d * 128 + 2 * tid] = make_float2(ox, oy);
    unsigned packed = (unsigned)(unsigned short)f32_to_bf16(ox) |
                      ((unsigned)(unsigned short)f32_to_bf16(oy) << 16);
    int unit = ((d >> 4) * 4 + (tid >> 4)) * 64 + ((tid >> 2) & 3) * 16 + (d & 15);
    afrag2u[unit * 4 + (tid & 3)] = packed;
}

// F=64: one wave per node, same pipelined 8-wide structure.
__global__ __launch_bounds__(64) void spmm64(const int2* __restrict__ rowinfo,
                                             const uint2* __restrict__ erec,
                                             const short* __restrict__ feat,
                                             const float* __restrict__ bias,
                                             float* __restrict__ out) {
    int d = blockIdx.x, tid = threadIdx.x;
    int2 ri = rowinfo[d];
    int beg = ri.x, end = ri.y;
    float acc = 0.f;
    const short* fp = feat + tid;
    int e = beg;
    if (end - beg >= 8) {
        uint2 r[8];
        #pragma unroll
        for (int j = 0; j < 8; ++j) r[j] = erec[e + j];
        for (; e + 16 <= end; e += 8) {
            float f[8];
            #pragma unroll
            for (int j = 0; j < 8; ++j) f[j] = bf16_to_f32(fp[r[j].x * 64u]);
            uint2 rn[8];
            #pragma unroll
            for (int j = 0; j < 8; ++j) rn[j] = erec[e + 8 + j];
            #pragma unroll
            for (int j = 0; j < 8; ++j) acc += __uint_as_float(r[j].y) * f[j];
            #pragma unroll
            for (int j = 0; j < 8; ++j) r[j] = rn[j];
        }
        {
            float f[8];
            #pragma unroll
            for (int j = 0; j < 8; ++j) f[j] = bf16_to_f32(fp[r[j].x * 64u]);
            #pragma unroll
            for (int j = 0; j < 8; ++j) acc += __uint_as_float(r[j].y) * f[j];
            e += 8;
        }
    }
    for (; e + 4 <= end; e += 4) {
        uint2 r0 = erec[e], r1 = erec[e + 1], r2 = erec[e + 2], r3 = erec[e + 3];
        float f0 = bf16_to_f32(fp[r0.x * 64u]);
        float f1 = bf16_to_f32(fp[r1.x * 64u]);
        float f2 = bf16_to_f32(fp[r2.x * 64u]);
        float f3 = bf16_to_f32(fp[r3.x * 64u]);
        acc += __uint_as_float(r0.y) * f0;
        acc += __uint_as_float(r1.y) * f1;
        acc += __uint_as_float(r2.y) * f2;
        acc += __uint_as_float(r3.y) * f3;
    }
    for (; e < end; ++e) {
        uint2 r = erec[e];
        acc += __uint_as_float(r.y) * bf16_to_f32(fp[r.x * 64u]);
    }
    out[(size_t)d * 64 + tid] = acc + bias[tid];
}

// ---------------- launch ----------------

extern "C" void kernel_launch(void* const* d_in, const int* in_sizes, int n_in,
                              void* d_out, int out_size, void* d_ws, size_t ws_size,
                              hipStream_t stream) {
    const float* x  = (const float*)d_in[0];
    const int*   ei = (const int*)d_in[1];
    const float* ew = (const float*)d_in[2];
    const float* W1 = (const float*)d_in[3];
    const float* b1 = (const float*)d_in[4];
    const float* W2 = (const float*)d_in[5];
    const float* b2 = (const float*)d_in[6];

    const int* dst = ei;
    const int* src = ei + N_EDGES;

    float* x1 = (float*)d_out;                          // [50000,128] fp32
    float* x2 = x1 + (size_t)N_NODES * F_HID;           // [50000,64]  fp32

    char* ws = (char*)d_ws;
    uint2*  erec     = (uint2*)ws;  ws += (size_t)NBUK * CAP * 8;         // 15.2 MB (slotted)
    uint2*  tmp      = (uint2*)ws;  ws += (size_t)NBUK * CAP * 8;         // 15.2 MB (slotted)
    short*  support1 = (short*)ws;  ws += (size_t)N_NODES * F_HID * 2;    // 12.8 MB
    short*  support2 = (short*)ws;  ws += (size_t)N_NODES * F_OUT * 2;    //  6.4 MB
    bf16x8* Afrag2   = (bf16x8*)ws; ws += (size_t)N_NODES * F_HID * 2;    // 12.8 MB
    bf16x8* Bfrag1   = (bf16x8*)ws; ws += (size_t)F_HID * F_IN * 2;       //  128 KB
    bf16x8* Bfrag2   = (bf16x8*)ws; ws += (size_t)F_OUT * F_HID * 2;      //   16 KB
    int2*   rowinfo  = (int2*)ws;   ws += (size_t)N_NODES * 8;            //  400 KB
    int*    gcnt     = (int*)ws;    ws += 400 * 4;

    const int NPB = (N_EDGES + EPB - 1) / EPB;          // 196 partition blocks
    const int MT  = N_NODES / 16;                       // 3125 row tiles (exact)

    // 1) CSR build (bucket partition, self-reserving fixed-capacity slots)
    hipMemsetAsync(gcnt, 0, NBUK * sizeof(int), stream);
    part_a<<<NPB, 256, 0, stream>>>(dst, src, ew, gcnt, tmp, N_EDGES);
    part_b<<<NBUK, 256, 0, stream>>>(tmp, gcnt, rowinfo, erec);

    // 2) weight prep (fragment-order bf16)
    wtrans_frag<F_IN, F_HID><<<32, 256, 0, stream>>>(W1, Bfrag1);
    wtrans_frag<F_HID, F_OUT><<<4, 256, 0, stream>>>(W2, Bfrag2);

    // 3) support1 = x @ W1 (bf16 out) — global_load_lds double-buffered GEMM
    {
        int blocks = (N_NODES + 63) / 64;               // 782
        mfma_gemm_s1<F_IN, F_HID><<<blocks, 256, 0, stream>>>(x, Bfrag1, support1, N_NODES);
    }

    // 4) x1 = relu(spmm(support1) + b1); also emits Afrag2 (bf16 fragment order)
    spmm128<<<N_NODES, 64, 0, stream>>>(rowinfo, erec, (const unsigned*)support1, b1, x1,
                                        (unsigned*)Afrag2);

    // 5) support2 = x1 @ W2 (bf16 out)
    mfma_gemm_frag<F_OUT, F_HID><<<(MT + 3) / 4, 256, 0, stream>>>(Afrag2, Bfrag2, support2, MT);

    // 6) x2 = spmm(support2) + b2
    spmm64<<<N_NODES, 64, 0, stream>>>(rowinfo, erec, support2, b2, x2);
}

// Round 9
// 349.186 us; speedup vs baseline: 1.0890x; 1.0049x over previous
//
#include <hip/hip_runtime.h>
#include <hip/hip_bf16.h>

#define N_NODES 50000
#define N_EDGES 1600000
#define F_IN    512
#define F_HID   128
#define F_OUT   64
#define NBUK    391          // ceil(50000/128) buckets of 128 nodes
#define EPB     8192         // edges per block in bucket passes
#define CAP     4864         // per-bucket slot capacity (mean 4092, +12 sigma)

typedef short bf16x8 __attribute__((ext_vector_type(8)));
typedef float f32x4  __attribute__((ext_vector_type(4)));

__device__ __forceinline__ short f32_to_bf16(float f) {
    unsigned u = __float_as_uint(f);
    u += 0x7FFF + ((u >> 16) & 1);          // RTNE
    return (short)(u >> 16);
}
__device__ __forceinline__ float bf16_to_f32(short s) {
    return __uint_as_float(((unsigned)(unsigned short)s) << 16);
}
__device__ __forceinline__ float bf16lo(unsigned u) { return __uint_as_float(u << 16); }
__device__ __forceinline__ float bf16hi(unsigned u) { return __uint_as_float(u & 0xFFFF0000u); }

// 8x f32 -> bf16x8 via packed HW convert (RNE); 4 instrs instead of 24.
__device__ __forceinline__ bf16x8 cvt8(float4 lo, float4 hi) {
    union { unsigned u[4]; bf16x8 v; } r;
    asm("v_cvt_pk_bf16_f32 %0, %1, %2" : "=v"(r.u[0]) : "v"(lo.x), "v"(lo.y));
    asm("v_cvt_pk_bf16_f32 %0, %1, %2" : "=v"(r.u[1]) : "v"(lo.z), "v"(lo.w));
    asm("v_cvt_pk_bf16_f32 %0, %1, %2" : "=v"(r.u[2]) : "v"(hi.x), "v"(hi.y));
    asm("v_cvt_pk_bf16_f32 %0, %1, %2" : "=v"(r.u[3]) : "v"(hi.z), "v"(hi.w));
    return r.v;
}

// async global->LDS, 16B per lane; LDS dest = wave-uniform base + lane*16 (HW rule)
__device__ __forceinline__ void gload16(const void* g, void* l) {
    __builtin_amdgcn_global_load_lds((const __attribute__((address_space(1))) void*)g,
                                     (__attribute__((address_space(3))) void*)l, 16, 0, 0);
}

// ---------------- CSR build: bucket partition with fixed-capacity slots ----------------

__global__ __launch_bounds__(256) void part_a(const int* __restrict__ dst,
                                              const int* __restrict__ src,
                                              const float* __restrict__ w,
                                              int* __restrict__ gcnt,
                                              uint2* __restrict__ tmp, int E) {
    __shared__ int h[NBUK];
    __shared__ int base[NBUK];
    for (int i = threadIdx.x; i < NBUK; i += 256) h[i] = 0;
    __syncthreads();
    int e0 = blockIdx.x * EPB;
    int e1 = min(e0 + EPB, E);
    for (int e = e0 + threadIdx.x; e < e1; e += 256)
        atomicAdd(&h[dst[e] >> 7], 1);
    __syncthreads();
    for (int i = threadIdx.x; i < NBUK; i += 256) {
        int c = h[i];
        base[i] = c ? atomicAdd(&gcnt[i], c) : 0;
        h[i] = 0;
    }
    __syncthreads();
    for (int e = e0 + threadIdx.x; e < e1; e += 256) {
        int d = dst[e];
        int b = d >> 7;
        int off = base[b] + atomicAdd(&h[b], 1);
        if (off < CAP)
            tmp[(size_t)b * CAP + off] = make_uint2(((unsigned)d << 16) | (unsigned)src[e],
                                                    __float_as_uint(w[e]));
    }
}

__global__ __launch_bounds__(256) void part_b(const uint2* __restrict__ tmp,
                                              const int* __restrict__ gcnt,
                                              int2* __restrict__ rowinfo,
                                              uint2* __restrict__ erec) {
    __shared__ int s[128];
    __shared__ int cur[128];
    int b = blockIdx.x, tid = threadIdx.x;
    int nb0 = b << 7;
    int r0 = b * CAP;
    int cnt_b = min(gcnt[b], CAP);
    int r1 = r0 + cnt_b;
    if (tid < 128) s[tid] = 0;
    __syncthreads();
    for (int i = r0 + tid; i < r1; i += 256)
        atomicAdd(&s[(tmp[i].x >> 16) - nb0], 1);
    __syncthreads();
    int v = (tid < 128) ? s[tid] : 0;
    #pragma unroll
    for (int off = 1; off < 128; off <<= 1) {
        int t = (tid >= off && tid < 128) ? s[tid - off] : 0;
        __syncthreads();
        if (tid < 128) s[tid] += t;
        __syncthreads();
    }
    if (tid < 128) {
        int ex = r0 + s[tid] - v;
        cur[tid] = ex;
        int node = nb0 + tid;
        if (node < N_NODES) rowinfo[node] = make_int2(ex, ex + v);
    }
    __syncthreads();
    for (int i = r0 + tid; i < r1; i += 256) {
        uint2 rec = tmp[i];
        int p = atomicAdd(&cur[(rec.x >> 16) - nb0], 1);
        erec[p] = make_uint2(rec.x & 0xFFFFu, rec.y);
    }
}

// ---------------- fragment-order conversions ----------------

// B fragment unit u = (kc*NT + nt)*64 + lane:
//   holds W[k = kc*32 + (lane>>4)*8 + j][n = nt*16 + (lane&15)]  (W is [KD][NC] row-major)
template<int KD, int NC>
__device__ __forceinline__ void wtrans_one(const float* __restrict__ W,
                                           bf16x8* __restrict__ Bfrag, int u) {
    constexpr int NT = NC / 16;
    int lane = u & 63;
    int nt   = (u >> 6) % NT;
    int kc   = u / (64 * NT);
    int n = nt * 16 + (lane & 15);
    int k = kc * 32 + (lane >> 4) * 8;
    bf16x8 f;
    #pragma unroll
    for (int j = 0; j < 8; ++j) f[j] = f32_to_bf16(W[(size_t)(k + j) * NC + n]);
    Bfrag[u] = f;
}

// both weight conversions in one launch (fewer serial dispatches)
__global__ __launch_bounds__(256) void wtrans_all(const float* __restrict__ W1,
                                                  const float* __restrict__ W2,
                                                  bf16x8* __restrict__ B1,
                                                  bf16x8* __restrict__ B2) {
    constexpr int U1 = (F_IN / 32) * (F_HID / 16) * 64;   // 8192
    constexpr int U2 = (F_HID / 32) * (F_OUT / 16) * 64;  // 1024
    int u = blockIdx.x * 256 + threadIdx.x;
    if (u < U1) wtrans_one<F_IN, F_HID>(W1, B1, u);
    else if (u < U1 + U2) wtrans_one<F_HID, F_OUT>(W2, B2, u - U1);
}

// ------------- GEMM1: 3-deep LDS ring, counted vmcnt (T3/T4), 64x128 tile, BK=32 -------------
// Per iteration: {vmcnt(8) -> s_barrier -> compute(s) -> s_barrier -> issue stage(s+3)}.
// Loads for stage s are issued 3 phases early and stay in flight ACROSS barriers
// (never drained to 0 in the main loop); epilogue drains 4 -> 0. Correctness:
// barrier1 + per-wave vmcnt(8) (identical issue schedule in every wave) => buffer s
// complete for all waves; barrier2 => all waves done reading ring[s%3] before overwrite.
template<int KD /*512*/, int NC /*128*/>
__global__ __launch_bounds__(256) void mfma_gemm_s1(const float* __restrict__ X,
                                                    const bf16x8* __restrict__ Bfrag,
                                                    short* __restrict__ C, int Mrows) {
    constexpr int S = KD / 32;            // 16 K-steps
    __shared__ char lds[3][16384];        // ring of 3: per buf A 8KB | B 8KB
    const int tid  = threadIdx.x;
    const int lane = tid & 63;
    const int wave = tid >> 6;
    const int wm = wave >> 1, wn = wave & 1;
    const int B0 = blockIdx.x * 64;
    const int r_lo = lane & 15, cg = lane >> 4;

    int rowA = B0 + wave * 16 + r_lo;
    if (rowA > Mrows - 1) rowA = Mrows - 1;          // clamp (garbage rows skipped on store)
    const char* gA = (const char*)(X + (size_t)rowA * KD) + cg * 32;   // +i*16 +s*128
    const char* gB = (const char*)Bfrag + (size_t)(wave * 2) * 1024 + (size_t)lane * 16; // +j*1024 +s*8192

    const int dA0 = (0 * 256 + wave * 64) * 16;      // wave-uniform LDS bases (+lane*16 by HW)
    const int dA1 = (1 * 256 + wave * 64) * 16;
    const int dB0 = 8192 + (wave * 2 + 0) * 1024;
    const int dB1 = 8192 + (wave * 2 + 1) * 1024;

    f32x4 acc[2][4];
    #pragma unroll
    for (int m = 0; m < 2; ++m)
        #pragma unroll
        for (int n = 0; n < 4; ++n) acc[m][n] = (f32x4){0.f, 0.f, 0.f, 0.f};

    auto issue_stage = [&](int s, char* L) {
        const char* a = gA + (size_t)s * 128;
        const char* b = gB + (size_t)s * 8192;
        gload16(a,        L + dA0);
        gload16(a + 16,   L + dA1);
        gload16(b,        L + dB0);
        gload16(b + 1024, L + dB1);
    };
    auto compute_step = [&](const char* L) {
        const char* A_ = L;
        const char* B_ = L + 8192;
        bf16x8 bb[4];
        #pragma unroll
        for (int n = 0; n < 4; ++n)
            bb[n] = *(const bf16x8*)(B_ + (wn * 4 + n) * 1024 + lane * 16);
        #pragma unroll
        for (int m = 0; m < 2; ++m) {
            int t = wm * 2 + m;
            float4 lo = *(const float4*)(A_ + (0 * 256 + t * 64 + lane) * 16);
            float4 hi = *(const float4*)(A_ + (1 * 256 + t * 64 + lane) * 16);
            bf16x8 a = cvt8(lo, hi);
            #pragma unroll
            for (int n = 0; n < 4; ++n)
                acc[m][n] = __builtin_amdgcn_mfma_f32_16x16x32_bf16(a, bb[n], acc[m][n], 0, 0, 0);
        }
    };

    // prologue: stages 0,1,2 in flight (12 loads/wave outstanding)
    issue_stage(0, lds[0]);
    issue_stage(1, lds[1]);
    issue_stage(2, lds[2]);

    for (int s = 0; s < S - 2; ++s) {                // s = 0..13
        asm volatile("s_waitcnt vmcnt(8)" ::: "memory");   // my stage-s loads landed
        asm volatile("s_barrier" ::: "memory");            // everyone's stage-s landed
        compute_step(lds[s % 3]);
        asm volatile("s_barrier" ::: "memory");            // all done reading ring[s%3]
        if (s + 3 < S) issue_stage(s + 3, lds[s % 3]);     // overwrite freed buffer
    }
    // epilogue: stages S-2, S-1 (outstanding 8 -> 4 -> 0)
    asm volatile("s_waitcnt vmcnt(4)" ::: "memory");
    asm volatile("s_barrier" ::: "memory");
    compute_step(lds[(S - 2) % 3]);
    asm volatile("s_waitcnt vmcnt(0)" ::: "memory");
    asm volatile("s_barrier" ::: "memory");
    compute_step(lds[(S - 1) % 3]);

    #pragma unroll
    for (int m = 0; m < 2; ++m) {
        int tile16 = (B0 >> 4) + wm * 2 + m;
        if (tile16 * 16 < Mrows) {
            #pragma unroll
            for (int n = 0; n < 4; ++n) {
                #pragma unroll
                for (int r = 0; r < 4; ++r) {
                    int grow = tile16 * 16 + cg * 4 + r;
                    C[(size_t)grow * NC + (wn * 4 + n) * 16 + r_lo] = f32_to_bf16(acc[m][n][r]);
                }
            }
        }
    }
}

// ---------------- fragment MFMA GEMM (A already in fragment order, bf16) ----------------

template<int NC, int KD>
__global__ __launch_bounds__(256) void mfma_gemm_frag(const bf16x8* __restrict__ Afrag,
                                                      const bf16x8* __restrict__ Bfrag,
                                                      short* __restrict__ C, int Mt) {
    constexpr int NT = NC / 16, KC = KD / 32;
    constexpr int PFA = (KC < 4) ? KC : 4;
    const int lane = threadIdx.x & 63;
    const int wave = threadIdx.x >> 6;
    const int tile = blockIdx.x * 4 + wave;
    if (tile >= Mt) return;

    const bf16x8* ap = Afrag + (size_t)tile * KC * 64 + lane;
    const bf16x8* bp = Bfrag + lane;

    f32x4 acc[NT];
    #pragma unroll
    for (int i = 0; i < NT; ++i) acc[i] = (f32x4){0.f, 0.f, 0.f, 0.f};

    bf16x8 abuf[PFA];
    #pragma unroll
    for (int i = 0; i < PFA; ++i) abuf[i] = ap[(size_t)i * 64];
    bf16x8 bbuf[NT];
    #pragma unroll
    for (int nt = 0; nt < NT; ++nt) bbuf[nt] = bp[(size_t)nt * 64];

    #pragma unroll
    for (int kc = 0; kc < KC; ++kc) {
        bf16x8 a = abuf[kc % PFA];
        int ka = kc + PFA; if (ka > KC - 1) ka = KC - 1;
        abuf[kc % PFA] = ap[(size_t)ka * 64];
        int kb = (kc + 1 < KC) ? kc + 1 : kc;
        bf16x8 bnew[NT];
        #pragma unroll
        for (int nt = 0; nt < NT; ++nt) {
            bnew[nt] = bp[((size_t)kb * NT + nt) * 64];
            acc[nt] = __builtin_amdgcn_mfma_f32_16x16x32_bf16(a, bbuf[nt], acc[nt], 0, 0, 0);
        }
        #pragma unroll
        for (int nt = 0; nt < NT; ++nt) bbuf[nt] = bnew[nt];
    }

    const int lrow = lane & 15, kgrp = lane >> 4;
    #pragma unroll
    for (int nt = 0; nt < NT; ++nt) {
        #pragma unroll
        for (int r = 0; r < 4; ++r) {
            int grow = tile * 16 + kgrp * 4 + r;
            C[(size_t)grow * NC + nt * 16 + lrow] = f32_to_bf16(acc[nt][r]);
        }
    }
}

// ---------------- SpMM gather ----------------

// F=128: one wave per node. 8-wide UNMASKED main loop, software-pipelined:
// erec batch for iteration i+1 issues while iteration i's feat gathers are in
// flight. Tails: 4-wide then scalar (no per-edge compares anywhere).
__global__ __launch_bounds__(64) void spmm128(const int2* __restrict__ rowinfo,
                                              const uint2* __restrict__ erec,
                                              const unsigned* __restrict__ featu,
                                              const float* __restrict__ bias,
                                              float* __restrict__ out,
                                              unsigned* __restrict__ afrag2u) {
    int d = blockIdx.x, tid = threadIdx.x;
    int2 ri = rowinfo[d];
    int beg = ri.x, end = ri.y;
    float a0 = 0.f, a1 = 0.f;
    const unsigned* fp = featu + tid;
    int e = beg;
    if (end - beg >= 8) {
        uint2 r[8];
        #pragma unroll
        for (int j = 0; j < 8; ++j) r[j] = erec[e + j];
        for (; e + 16 <= end; e += 8) {
            unsigned f[8];
            #pragma unroll
            for (int j = 0; j < 8; ++j) f[j] = fp[r[j].x * 64u];
            uint2 rn[8];
            #pragma unroll
            for (int j = 0; j < 8; ++j) rn[j] = erec[e + 8 + j];
            #pragma unroll
            for (int j = 0; j < 8; ++j) {
                float w = __uint_as_float(r[j].y);
                a0 += w * bf16lo(f[j]);
                a1 += w * bf16hi(f[j]);
            }
            #pragma unroll
            for (int j = 0; j < 8; ++j) r[j] = rn[j];
        }
        {   // drain: last full batch, no prefetch
            unsigned f[8];
            #pragma unroll
            for (int j = 0; j < 8; ++j) f[j] = fp[r[j].x * 64u];
            #pragma unroll
            for (int j = 0; j < 8; ++j) {
                float w = __uint_as_float(r[j].y);
                a0 += w * bf16lo(f[j]);
                a1 += w * bf16hi(f[j]);
            }
            e += 8;
        }
    }
    for (; e + 4 <= end; e += 4) {
        uint2 r0 = erec[e], r1 = erec[e + 1], r2 = erec[e + 2], r3 = erec[e + 3];
        unsigned f0 = fp[r0.x * 64u];
        unsigned f1 = fp[r1.x * 64u];
        unsigned f2 = fp[r2.x * 64u];
        unsigned f3 = fp[r3.x * 64u];
        float w0 = __uint_as_float(r0.y), w1 = __uint_as_float(r1.y);
        float w2 = __uint_as_float(r2.y), w3 = __uint_as_float(r3.y);
        a0 += w0 * bf16lo(f0); a1 += w0 * bf16hi(f0);
        a0 += w1 * bf16lo(f1); a1 += w1 * bf16hi(f1);
        a0 += w2 * bf16lo(f2); a1 += w2 * bf16hi(f2);
        a0 += w3 * bf16lo(f3); a1 += w3 * bf16hi(f3);
    }
    for (; e < end; ++e) {
        uint2 r = erec[e];
        unsigned f = fp[r.x * 64u];
        float w = __uint_as_float(r.y);
        a0 += w * bf16lo(f); a1 += w * bf16hi(f);
    }
    float ox = fmaxf(a0 + bias[2 * tid], 0.f);
    float oy = fmaxf(a1 + bias[2 * tid + 1], 0.f);
    *(float2*)&out[(size_t)d * 128 + 2 * tid] = make_float2(ox, oy);
    unsigned packed = (unsigned)(unsigned short)f32_to_bf16(ox) |
                      ((unsigned)(unsigned short)f32_to_bf16(oy) << 16);
    int unit = ((d >> 4) * 4 + (tid >> 4)) * 64 + ((tid >> 2) & 3) * 16 + (d & 15);
    afrag2u[unit * 4 + (tid & 3)] = packed;
}

// F=64: one wave per node, same pipelined 8-wide structure.
__global__ __launch_bounds__(64) void spmm64(const int2* __restrict__ rowinfo,
                                             const uint2* __restrict__ erec,
                                             const short* __restrict__ feat,
                                             const float* __restrict__ bias,
                                             float* __restrict__ out) {
    int d = blockIdx.x, tid = threadIdx.x;
    int2 ri = rowinfo[d];
    int beg = ri.x, end = ri.y;
    float acc = 0.f;
    const short* fp = feat + tid;
    int e = beg;
    if (end - beg >= 8) {
        uint2 r[8];
        #pragma unroll
        for (int j = 0; j < 8; ++j) r[j] = erec[e + j];
        for (; e + 16 <= end; e += 8) {
            float f[8];
            #pragma unroll
            for (int j = 0; j < 8; ++j) f[j] = bf16_to_f32(fp[r[j].x * 64u]);
            uint2 rn[8];
            #pragma unroll
            for (int j = 0; j < 8; ++j) rn[j] = erec[e + 8 + j];
            #pragma unroll
            for (int j = 0; j < 8; ++j) acc += __uint_as_float(r[j].y) * f[j];
            #pragma unroll
            for (int j = 0; j < 8; ++j) r[j] = rn[j];
        }
        {
            float f[8];
            #pragma unroll
            for (int j = 0; j < 8; ++j) f[j] = bf16_to_f32(fp[r[j].x * 64u]);
            #pragma unroll
            for (int j = 0; j < 8; ++j) acc += __uint_as_float(r[j].y) * f[j];
            e += 8;
        }
    }
    for (; e + 4 <= end; e += 4) {
        uint2 r0 = erec[e], r1 = erec[e + 1], r2 = erec[e + 2], r3 = erec[e + 3];
        float f0 = bf16_to_f32(fp[r0.x * 64u]);
        float f1 = bf16_to_f32(fp[r1.x * 64u]);
        float f2 = bf16_to_f32(fp[r2.x * 64u]);
        float f3 = bf16_to_f32(fp[r3.x * 64u]);
        acc += __uint_as_float(r0.y) * f0;
        acc += __uint_as_float(r1.y) * f1;
        acc += __uint_as_float(r2.y) * f2;
        acc += __uint_as_float(r3.y) * f3;
    }
    for (; e < end; ++e) {
        uint2 r = erec[e];
        acc += __uint_as_float(r.y) * bf16_to_f32(fp[r.x * 64u]);
    }
    out[(size_t)d * 64 + tid] = acc + bias[tid];
}

// ---------------- launch ----------------

extern "C" void kernel_launch(void* const* d_in, const int* in_sizes, int n_in,
                              void* d_out, int out_size, void* d_ws, size_t ws_size,
                              hipStream_t stream) {
    const float* x  = (const float*)d_in[0];
    const int*   ei = (const int*)d_in[1];
    const float* ew = (const float*)d_in[2];
    const float* W1 = (const float*)d_in[3];
    const float* b1 = (const float*)d_in[4];
    const float* W2 = (const float*)d_in[5];
    const float* b2 = (const float*)d_in[6];

    const int* dst = ei;
    const int* src = ei + N_EDGES;

    float* x1 = (float*)d_out;                          // [50000,128] fp32
    float* x2 = x1 + (size_t)N_NODES * F_HID;           // [50000,64]  fp32

    char* ws = (char*)d_ws;
    uint2*  erec     = (uint2*)ws;  ws += (size_t)NBUK * CAP * 8;         // 15.2 MB (slotted)
    uint2*  tmp      = (uint2*)ws;  ws += (size_t)NBUK * CAP * 8;         // 15.2 MB (slotted)
    short*  support1 = (short*)ws;  ws += (size_t)N_NODES * F_HID * 2;    // 12.8 MB
    short*  support2 = (short*)ws;  ws += (size_t)N_NODES * F_OUT * 2;    //  6.4 MB
    bf16x8* Afrag2   = (bf16x8*)ws; ws += (size_t)N_NODES * F_HID * 2;    // 12.8 MB
    bf16x8* Bfrag1   = (bf16x8*)ws; ws += (size_t)F_HID * F_IN * 2;       //  128 KB
    bf16x8* Bfrag2   = (bf16x8*)ws; ws += (size_t)F_OUT * F_HID * 2;      //   16 KB
    int2*   rowinfo  = (int2*)ws;   ws += (size_t)N_NODES * 8;            //  400 KB
    int*    gcnt     = (int*)ws;    ws += 400 * 4;

    const int NPB = (N_EDGES + EPB - 1) / EPB;          // 196 partition blocks
    const int MT  = N_NODES / 16;                       // 3125 row tiles (exact)

    // 1) CSR build (bucket partition, self-reserving fixed-capacity slots)
    hipMemsetAsync(gcnt, 0, NBUK * sizeof(int), stream);
    part_a<<<NPB, 256, 0, stream>>>(dst, src, ew, gcnt, tmp, N_EDGES);
    part_b<<<NBUK, 256, 0, stream>>>(tmp, gcnt, rowinfo, erec);

    // 2) weight prep (fragment-order bf16, single launch)
    wtrans_all<<<36, 256, 0, stream>>>(W1, W2, Bfrag1, Bfrag2);

    // 3) support1 = x @ W1 (bf16 out) — 3-deep ring, counted-vmcnt GEMM
    {
        int blocks = (N_NODES + 63) / 64;               // 782
        mfma_gemm_s1<F_IN, F_HID><<<blocks, 256, 0, stream>>>(x, Bfrag1, support1, N_NODES);
    }

    // 4) x1 = relu(spmm(support1) + b1); also emits Afrag2 (bf16 fragment order)
    spmm128<<<N_NODES, 64, 0, stream>>>(rowinfo, erec, (const unsigned*)support1, b1, x1,
                                        (unsigned*)Afrag2);

    // 5) support2 = x1 @ W2 (bf16 out)
    mfma_gemm_frag<F_OUT, F_HID><<<(MT + 3) / 4, 256, 0, stream>>>(Afrag2, Bfrag2, support2, MT);

    // 6) x2 = spmm(support2) + b2
    spmm64<<<N_NODES, 64, 0, stream>>>(rowinfo, erec, support2, b2, x2);
}

// Round 10
// 332.955 us; speedup vs baseline: 1.1421x; 1.0487x over previous
//
#include <hip/hip_runtime.h>
#include <hip/hip_bf16.h>

#define N_NODES 50000
#define N_EDGES 1600000
#define F_IN    512
#define F_HID   128
#define F_OUT   64
#define NBUK    391          // ceil(50000/128) buckets of 128 nodes
#define EPB     2048         // edges per block in part_a (782 blocks)
#define CAP     4864         // per-bucket slot capacity (mean 4092, +12 sigma)

typedef short bf16x8 __attribute__((ext_vector_type(8)));
typedef float f32x4  __attribute__((ext_vector_type(4)));

__device__ __forceinline__ short f32_to_bf16(float f) {
    unsigned u = __float_as_uint(f);
    u += 0x7FFF + ((u >> 16) & 1);          // RTNE
    return (short)(u >> 16);
}
__device__ __forceinline__ float bf16_to_f32(short s) {
    return __uint_as_float(((unsigned)(unsigned short)s) << 16);
}
__device__ __forceinline__ float bf16lo(unsigned u) { return __uint_as_float(u << 16); }
__device__ __forceinline__ float bf16hi(unsigned u) { return __uint_as_float(u & 0xFFFF0000u); }

// 8x f32 -> bf16x8 via packed HW convert (RNE); 4 instrs instead of 24.
__device__ __forceinline__ bf16x8 cvt8(float4 lo, float4 hi) {
    union { unsigned u[4]; bf16x8 v; } r;
    asm("v_cvt_pk_bf16_f32 %0, %1, %2" : "=v"(r.u[0]) : "v"(lo.x), "v"(lo.y));
    asm("v_cvt_pk_bf16_f32 %0, %1, %2" : "=v"(r.u[1]) : "v"(lo.z), "v"(lo.w));
    asm("v_cvt_pk_bf16_f32 %0, %1, %2" : "=v"(r.u[2]) : "v"(hi.x), "v"(hi.y));
    asm("v_cvt_pk_bf16_f32 %0, %1, %2" : "=v"(r.u[3]) : "v"(hi.z), "v"(hi.w));
    return r.v;
}

// async global->LDS, 16B per lane; LDS dest = wave-uniform base + lane*16 (HW rule)
__device__ __forceinline__ void gload16(const void* g, void* l) {
    __builtin_amdgcn_global_load_lds((const __attribute__((address_space(1))) void*)g,
                                     (__attribute__((address_space(3))) void*)l, 16, 0, 0);
}

// ---------------- CSR build: LDS-binned bucket partition ----------------

// part_a: 782 blocks x 2048 edges. Bin records into LDS by bucket, flush with
// coalesced runs (consecutive LDS slots -> consecutive tmp addresses).
__global__ __launch_bounds__(256) void part_a(const int* __restrict__ dst,
                                              const int* __restrict__ src,
                                              const float* __restrict__ w,
                                              int* __restrict__ gcnt,
                                              uint2* __restrict__ tmp, int E) {
    __shared__ int h[NBUK];          // per-bucket count in this block
    __shared__ int base_[NBUK];      // global base per bucket (this block's reservation)
    __shared__ int ex[NBUK];         // inclusive scan of h
    __shared__ int curz[NBUK];       // 0-based per-bucket cursor
    __shared__ int   ldst[EPB];      // cached dst values
    __shared__ uint2 rec[EPB];       // binned records
    __shared__ int   tgt[EPB];       // global target slot per LDS slot (-1 = drop)
    const int tid = threadIdx.x;
    for (int i = tid; i < NBUK; i += 256) { h[i] = 0; curz[i] = 0; }
    __syncthreads();
    int e0 = blockIdx.x * EPB;
    int e1 = min(e0 + EPB, E);
    int cnt = e1 - e0;
    for (int e = e0 + tid; e < e1; e += 256) {
        int d = dst[e];
        ldst[e - e0] = d;
        atomicAdd(&h[d >> 7], 1);
    }
    __syncthreads();
    for (int i = tid; i < NBUK; i += 256) {
        int c = h[i];
        base_[i] = c ? atomicAdd(&gcnt[i], c) : 0;
        ex[i] = c;
    }
    __syncthreads();
    // inclusive Hillis-Steele scan of ex[0..NBUK)
    for (int off = 1; off < NBUK; off <<= 1) {
        int i0 = tid, i1 = tid + 256;
        int t0 = 0, t1 = 0;
        if (i0 < NBUK && i0 >= off) t0 = ex[i0 - off];
        if (i1 < NBUK && i1 >= off) t1 = ex[i1 - off];
        __syncthreads();
        if (i0 < NBUK && i0 >= off) ex[i0] += t0;
        if (i1 < NBUK && i1 >= off) ex[i1] += t1;
        __syncthreads();
    }
    // bin into LDS
    for (int e = e0 + tid; e < e1; e += 256) {
        int d = ldst[e - e0];
        int b = d >> 7;
        int j0 = atomicAdd(&curz[b], 1);                 // 0-based within bucket
        int slot = ex[b] - h[b] + j0;                    // exclusive-scan base + j0
        rec[slot] = make_uint2(((unsigned)d << 16) | (unsigned)src[e],
                               __float_as_uint(w[e]));
        int goff = base_[b] + j0;
        tgt[slot] = (goff < CAP) ? b * CAP + goff : -1;
    }
    __syncthreads();
    // coalesced-run flush
    for (int i = tid; i < cnt; i += 256) {
        int t = tgt[i];
        if (t >= 0) tmp[t] = rec[i];
    }
}

// part_b: load bucket records to LDS once, hist+scan+scatter in LDS, flush
// erec with perfectly coalesced sequential writes.
__global__ __launch_bounds__(256) void part_b(const uint2* __restrict__ tmp,
                                              const int* __restrict__ gcnt,
                                              int2* __restrict__ rowinfo,
                                              uint2* __restrict__ erec) {
    __shared__ int s[128];
    __shared__ int cur[128];
    __shared__ uint2 rec[CAP];       // 38912 B
    __shared__ uint2 ord[CAP];       // 38912 B
    int b = blockIdx.x, tid = threadIdx.x;
    int nb0 = b << 7;
    int r0 = b * CAP;
    int cnt_b = min(gcnt[b], CAP);
    if (tid < 128) s[tid] = 0;
    __syncthreads();
    for (int i = tid; i < cnt_b; i += 256) {
        uint2 r = tmp[r0 + i];
        rec[i] = r;
        atomicAdd(&s[(r.x >> 16) - nb0], 1);
    }
    __syncthreads();
    int v = (tid < 128) ? s[tid] : 0;
    #pragma unroll
    for (int off = 1; off < 128; off <<= 1) {
        int t = (tid >= off && tid < 128) ? s[tid - off] : 0;
        __syncthreads();
        if (tid < 128) s[tid] += t;
        __syncthreads();
    }
    if (tid < 128) {
        int ex = s[tid] - v;                             // block-local exclusive
        cur[tid] = ex;
        int node = nb0 + tid;
        if (node < N_NODES) rowinfo[node] = make_int2(r0 + ex, r0 + ex + v);
    }
    __syncthreads();
    for (int i = tid; i < cnt_b; i += 256) {
        uint2 r = rec[i];
        int p = atomicAdd(&cur[(r.x >> 16) - nb0], 1);   // block-local position
        ord[p] = make_uint2(r.x & 0xFFFFu, r.y);
    }
    __syncthreads();
    for (int i = tid; i < cnt_b; i += 256)
        erec[r0 + i] = ord[i];
}

// ---------------- fragment-order conversions ----------------

// B fragment unit u = (kc*NT + nt)*64 + lane:
//   holds W[k = kc*32 + (lane>>4)*8 + j][n = nt*16 + (lane&15)]  (W is [KD][NC] row-major)
template<int KD, int NC>
__device__ __forceinline__ void wtrans_one(const float* __restrict__ W,
                                           bf16x8* __restrict__ Bfrag, int u) {
    constexpr int NT = NC / 16;
    int lane = u & 63;
    int nt   = (u >> 6) % NT;
    int kc   = u / (64 * NT);
    int n = nt * 16 + (lane & 15);
    int k = kc * 32 + (lane >> 4) * 8;
    bf16x8 f;
    #pragma unroll
    for (int j = 0; j < 8; ++j) f[j] = f32_to_bf16(W[(size_t)(k + j) * NC + n]);
    Bfrag[u] = f;
}

// both weight conversions in one launch (fewer serial dispatches)
__global__ __launch_bounds__(256) void wtrans_all(const float* __restrict__ W1,
                                                  const float* __restrict__ W2,
                                                  bf16x8* __restrict__ B1,
                                                  bf16x8* __restrict__ B2) {
    constexpr int U1 = (F_IN / 32) * (F_HID / 16) * 64;   // 8192
    constexpr int U2 = (F_HID / 32) * (F_OUT / 16) * 64;  // 1024
    int u = blockIdx.x * 256 + threadIdx.x;
    if (u < U1) wtrans_one<F_IN, F_HID>(W1, B1, u);
    else if (u < U1 + U2) wtrans_one<F_HID, F_OUT>(W2, B2, u - U1);
}

// ------------- GEMM1: 3-deep LDS ring, counted vmcnt (T3/T4), 64x128 tile, BK=32 -------------
template<int KD /*512*/, int NC /*128*/>
__global__ __launch_bounds__(256) void mfma_gemm_s1(const float* __restrict__ X,
                                                    const bf16x8* __restrict__ Bfrag,
                                                    short* __restrict__ C, int Mrows) {
    constexpr int S = KD / 32;            // 16 K-steps
    __shared__ char lds[3][16384];        // ring of 3: per buf A 8KB | B 8KB
    const int tid  = threadIdx.x;
    const int lane = tid & 63;
    const int wave = tid >> 6;
    const int wm = wave >> 1, wn = wave & 1;
    const int B0 = blockIdx.x * 64;
    const int r_lo = lane & 15, cg = lane >> 4;

    int rowA = B0 + wave * 16 + r_lo;
    if (rowA > Mrows - 1) rowA = Mrows - 1;          // clamp (garbage rows skipped on store)
    const char* gA = (const char*)(X + (size_t)rowA * KD) + cg * 32;   // +i*16 +s*128
    const char* gB = (const char*)Bfrag + (size_t)(wave * 2) * 1024 + (size_t)lane * 16; // +j*1024 +s*8192

    const int dA0 = (0 * 256 + wave * 64) * 16;      // wave-uniform LDS bases (+lane*16 by HW)
    const int dA1 = (1 * 256 + wave * 64) * 16;
    const int dB0 = 8192 + (wave * 2 + 0) * 1024;
    const int dB1 = 8192 + (wave * 2 + 1) * 1024;

    f32x4 acc[2][4];
    #pragma unroll
    for (int m = 0; m < 2; ++m)
        #pragma unroll
        for (int n = 0; n < 4; ++n) acc[m][n] = (f32x4){0.f, 0.f, 0.f, 0.f};

    auto issue_stage = [&](int s, char* L) {
        const char* a = gA + (size_t)s * 128;
        const char* b = gB + (size_t)s * 8192;
        gload16(a,        L + dA0);
        gload16(a + 16,   L + dA1);
        gload16(b,        L + dB0);
        gload16(b + 1024, L + dB1);
    };
    auto compute_step = [&](const char* L) {
        const char* A_ = L;
        const char* B_ = L + 8192;
        bf16x8 bb[4];
        #pragma unroll
        for (int n = 0; n < 4; ++n)
            bb[n] = *(const bf16x8*)(B_ + (wn * 4 + n) * 1024 + lane * 16);
        #pragma unroll
        for (int m = 0; m < 2; ++m) {
            int t = wm * 2 + m;
            float4 lo = *(const float4*)(A_ + (0 * 256 + t * 64 + lane) * 16);
            float4 hi = *(const float4*)(A_ + (1 * 256 + t * 64 + lane) * 16);
            bf16x8 a = cvt8(lo, hi);
            #pragma unroll
            for (int n = 0; n < 4; ++n)
                acc[m][n] = __builtin_amdgcn_mfma_f32_16x16x32_bf16(a, bb[n], acc[m][n], 0, 0, 0);
        }
    };

    // prologue: stages 0,1,2 in flight (12 loads/wave outstanding)
    issue_stage(0, lds[0]);
    issue_stage(1, lds[1]);
    issue_stage(2, lds[2]);

    for (int s = 0; s < S - 2; ++s) {                // s = 0..13
        asm volatile("s_waitcnt vmcnt(8)" ::: "memory");   // my stage-s loads landed
        asm volatile("s_barrier" ::: "memory");            // everyone's stage-s landed
        compute_step(lds[s % 3]);
        asm volatile("s_barrier" ::: "memory");            // all done reading ring[s%3]
        if (s + 3 < S) issue_stage(s + 3, lds[s % 3]);     // overwrite freed buffer
    }
    // epilogue: stages S-2, S-1 (outstanding 8 -> 4 -> 0)
    asm volatile("s_waitcnt vmcnt(4)" ::: "memory");
    asm volatile("s_barrier" ::: "memory");
    compute_step(lds[(S - 2) % 3]);
    asm volatile("s_waitcnt vmcnt(0)" ::: "memory");
    asm volatile("s_barrier" ::: "memory");
    compute_step(lds[(S - 1) % 3]);

    #pragma unroll
    for (int m = 0; m < 2; ++m) {
        int tile16 = (B0 >> 4) + wm * 2 + m;
        if (tile16 * 16 < Mrows) {
            #pragma unroll
            for (int n = 0; n < 4; ++n) {
                #pragma unroll
                for (int r = 0; r < 4; ++r) {
                    int grow = tile16 * 16 + cg * 4 + r;
                    C[(size_t)grow * NC + (wn * 4 + n) * 16 + r_lo] = f32_to_bf16(acc[m][n][r]);
                }
            }
        }
    }
}

// ---------------- fragment MFMA GEMM (A already in fragment order, bf16) ----------------

template<int NC, int KD>
__global__ __launch_bounds__(256) void mfma_gemm_frag(const bf16x8* __restrict__ Afrag,
                                                      const bf16x8* __restrict__ Bfrag,
                                                      short* __restrict__ C, int Mt) {
    constexpr int NT = NC / 16, KC = KD / 32;
    constexpr int PFA = (KC < 4) ? KC : 4;
    const int lane = threadIdx.x & 63;
    const int wave = threadIdx.x >> 6;
    const int tile = blockIdx.x * 4 + wave;
    if (tile >= Mt) return;

    const bf16x8* ap = Afrag + (size_t)tile * KC * 64 + lane;
    const bf16x8* bp = Bfrag + lane;

    f32x4 acc[NT];
    #pragma unroll
    for (int i = 0; i < NT; ++i) acc[i] = (f32x4){0.f, 0.f, 0.f, 0.f};

    bf16x8 abuf[PFA];
    #pragma unroll
    for (int i = 0; i < PFA; ++i) abuf[i] = ap[(size_t)i * 64];
    bf16x8 bbuf[NT];
    #pragma unroll
    for (int nt = 0; nt < NT; ++nt) bbuf[nt] = bp[(size_t)nt * 64];

    #pragma unroll
    for (int kc = 0; kc < KC; ++kc) {
        bf16x8 a = abuf[kc % PFA];
        int ka = kc + PFA; if (ka > KC - 1) ka = KC - 1;
        abuf[kc % PFA] = ap[(size_t)ka * 64];
        int kb = (kc + 1 < KC) ? kc + 1 : kc;
        bf16x8 bnew[NT];
        #pragma unroll
        for (int nt = 0; nt < NT; ++nt) {
            bnew[nt] = bp[((size_t)kb * NT + nt) * 64];
            acc[nt] = __builtin_amdgcn_mfma_f32_16x16x32_bf16(a, bbuf[nt], acc[nt], 0, 0, 0);
        }
        #pragma unroll
        for (int nt = 0; nt < NT; ++nt) bbuf[nt] = bnew[nt];
    }

    const int lrow = lane & 15, kgrp = lane >> 4;
    #pragma unroll
    for (int nt = 0; nt < NT; ++nt) {
        #pragma unroll
        for (int r = 0; r < 4; ++r) {
            int grow = tile * 16 + kgrp * 4 + r;
            C[(size_t)grow * NC + nt * 16 + lrow] = f32_to_bf16(acc[nt][r]);
        }
    }
}

// ---------------- SpMM gather ----------------

// F=128: one wave per node. 8-wide UNMASKED main loop, software-pipelined.
__global__ __launch_bounds__(64) void spmm128(const int2* __restrict__ rowinfo,
                                              const uint2* __restrict__ erec,
                                              const unsigned* __restrict__ featu,
                                              const float* __restrict__ bias,
                                              float* __restrict__ out,
                                              unsigned* __restrict__ afrag2u) {
    int d = blockIdx.x, tid = threadIdx.x;
    int2 ri = rowinfo[d];
    int beg = ri.x, end = ri.y;
    float a0 = 0.f, a1 = 0.f;
    const unsigned* fp = featu + tid;
    int e = beg;
    if (end - beg >= 8) {
        uint2 r[8];
        #pragma unroll
        for (int j = 0; j < 8; ++j) r[j] = erec[e + j];
        for (; e + 16 <= end; e += 8) {
            unsigned f[8];
            #pragma unroll
            for (int j = 0; j < 8; ++j) f[j] = fp[r[j].x * 64u];
            uint2 rn[8];
            #pragma unroll
            for (int j = 0; j < 8; ++j) rn[j] = erec[e + 8 + j];
            #pragma unroll
            for (int j = 0; j < 8; ++j) {
                float w = __uint_as_float(r[j].y);
                a0 += w * bf16lo(f[j]);
                a1 += w * bf16hi(f[j]);
            }
            #pragma unroll
            for (int j = 0; j < 8; ++j) r[j] = rn[j];
        }
        {   // drain: last full batch, no prefetch
            unsigned f[8];
            #pragma unroll
            for (int j = 0; j < 8; ++j) f[j] = fp[r[j].x * 64u];
            #pragma unroll
            for (int j = 0; j < 8; ++j) {
                float w = __uint_as_float(r[j].y);
                a0 += w * bf16lo(f[j]);
                a1 += w * bf16hi(f[j]);
            }
            e += 8;
        }
    }
    for (; e + 4 <= end; e += 4) {
        uint2 r0 = erec[e], r1 = erec[e + 1], r2 = erec[e + 2], r3 = erec[e + 3];
        unsigned f0 = fp[r0.x * 64u];
        unsigned f1 = fp[r1.x * 64u];
        unsigned f2 = fp[r2.x * 64u];
        unsigned f3 = fp[r3.x * 64u];
        float w0 = __uint_as_float(r0.y), w1 = __uint_as_float(r1.y);
        float w2 = __uint_as_float(r2.y), w3 = __uint_as_float(r3.y);
        a0 += w0 * bf16lo(f0); a1 += w0 * bf16hi(f0);
        a0 += w1 * bf16lo(f1); a1 += w1 * bf16hi(f1);
        a0 += w2 * bf16lo(f2); a1 += w2 * bf16hi(f2);
        a0 += w3 * bf16lo(f3); a1 += w3 * bf16hi(f3);
    }
    for (; e < end; ++e) {
        uint2 r = erec[e];
        unsigned f = fp[r.x * 64u];
        float w = __uint_as_float(r.y);
        a0 += w * bf16lo(f); a1 += w * bf16hi(f);
    }
    float ox = fmaxf(a0 + bias[2 * tid], 0.f);
    float oy = fmaxf(a1 + bias[2 * tid + 1], 0.f);
    *(float2*)&out[(size_t)d * 128 + 2 * tid] = make_float2(ox, oy);
    unsigned packed = (unsigned)(unsigned short)f32_to_bf16(ox) |
                      ((unsigned)(unsigned short)f32_to_bf16(oy) << 16);
    int unit = ((d >> 4) * 4 + (tid >> 4)) * 64 + ((tid >> 2) & 3) * 16 + (d & 15);
    afrag2u[unit * 4 + (tid & 3)] = packed;
}

// F=64: one wave per node, same pipelined 8-wide structure.
__global__ __launch_bounds__(64) void spmm64(const int2* __restrict__ rowinfo,
                                             const uint2* __restrict__ erec,
                                             const short* __restrict__ feat,
                                             const float* __restrict__ bias,
                                             float* __restrict__ out) {
    int d = blockIdx.x, tid = threadIdx.x;
    int2 ri = rowinfo[d];
    int beg = ri.x, end = ri.y;
    float acc = 0.f;
    const short* fp = feat + tid;
    int e = beg;
    if (end - beg >= 8) {
        uint2 r[8];
        #pragma unroll
        for (int j = 0; j < 8; ++j) r[j] = erec[e + j];
        for (; e + 16 <= end; e += 8) {
            float f[8];
            #pragma unroll
            for (int j = 0; j < 8; ++j) f[j] = bf16_to_f32(fp[r[j].x * 64u]);
            uint2 rn[8];
            #pragma unroll
            for (int j = 0; j < 8; ++j) rn[j] = erec[e + 8 + j];
            #pragma unroll
            for (int j = 0; j < 8; ++j) acc += __uint_as_float(r[j].y) * f[j];
            #pragma unroll
            for (int j = 0; j < 8; ++j) r[j] = rn[j];
        }
        {
            float f[8];
            #pragma unroll
            for (int j = 0; j < 8; ++j) f[j] = bf16_to_f32(fp[r[j].x * 64u]);
            #pragma unroll
            for (int j = 0; j < 8; ++j) acc += __uint_as_float(r[j].y) * f[j];
            e += 8;
        }
    }
    for (; e + 4 <= end; e += 4) {
        uint2 r0 = erec[e], r1 = erec[e + 1], r2 = erec[e + 2], r3 = erec[e + 3];
        float f0 = bf16_to_f32(fp[r0.x * 64u]);
        float f1 = bf16_to_f32(fp[r1.x * 64u]);
        float f2 = bf16_to_f32(fp[r2.x * 64u]);
        float f3 = bf16_to_f32(fp[r3.x * 64u]);
        acc += __uint_as_float(r0.y) * f0;
        acc += __uint_as_float(r1.y) * f1;
        acc += __uint_as_float(r2.y) * f2;
        acc += __uint_as_float(r3.y) * f3;
    }
    for (; e < end; ++e) {
        uint2 r = erec[e];
        acc += __uint_as_float(r.y) * bf16_to_f32(fp[r.x * 64u]);
    }
    out[(size_t)d * 64 + tid] = acc + bias[tid];
}

// ---------------- launch ----------------

extern "C" void kernel_launch(void* const* d_in, const int* in_sizes, int n_in,
                              void* d_out, int out_size, void* d_ws, size_t ws_size,
                              hipStream_t stream) {
    const float* x  = (const float*)d_in[0];
    const int*   ei = (const int*)d_in[1];
    const float* ew = (const float*)d_in[2];
    const float* W1 = (const float*)d_in[3];
    const float* b1 = (const float*)d_in[4];
    const float* W2 = (const float*)d_in[5];
    const float* b2 = (const float*)d_in[6];

    const int* dst = ei;
    const int* src = ei + N_EDGES;

    float* x1 = (float*)d_out;                          // [50000,128] fp32
    float* x2 = x1 + (size_t)N_NODES * F_HID;           // [50000,64]  fp32

    char* ws = (char*)d_ws;
    uint2*  erec     = (uint2*)ws;  ws += (size_t)NBUK * CAP * 8;         // 15.2 MB (slotted)
    uint2*  tmp      = (uint2*)ws;  ws += (size_t)NBUK * CAP * 8;         // 15.2 MB (slotted)
    short*  support1 = (short*)ws;  ws += (size_t)N_NODES * F_HID * 2;    // 12.8 MB
    short*  support2 = (short*)ws;  ws += (size_t)N_NODES * F_OUT * 2;    //  6.4 MB
    bf16x8* Afrag2   = (bf16x8*)ws; ws += (size_t)N_NODES * F_HID * 2;    // 12.8 MB
    bf16x8* Bfrag1   = (bf16x8*)ws; ws += (size_t)F_HID * F_IN * 2;       //  128 KB
    bf16x8* Bfrag2   = (bf16x8*)ws; ws += (size_t)F_OUT * F_HID * 2;      //   16 KB
    int2*   rowinfo  = (int2*)ws;   ws += (size_t)N_NODES * 8;            //  400 KB
    int*    gcnt     = (int*)ws;    ws += 400 * 4;

    const int NPB = (N_EDGES + EPB - 1) / EPB;          // 782 partition blocks
    const int MT  = N_NODES / 16;                       // 3125 row tiles (exact)

    // 1) CSR build (LDS-binned bucket partition)
    hipMemsetAsync(gcnt, 0, NBUK * sizeof(int), stream);
    part_a<<<NPB, 256, 0, stream>>>(dst, src, ew, gcnt, tmp, N_EDGES);
    part_b<<<NBUK, 256, 0, stream>>>(tmp, gcnt, rowinfo, erec);

    // 2) weight prep (fragment-order bf16, single launch)
    wtrans_all<<<36, 256, 0, stream>>>(W1, W2, Bfrag1, Bfrag2);

    // 3) support1 = x @ W1 (bf16 out) — 3-deep ring, counted-vmcnt GEMM
    {
        int blocks = (N_NODES + 63) / 64;               // 782
        mfma_gemm_s1<F_IN, F_HID><<<blocks, 256, 0, stream>>>(x, Bfrag1, support1, N_NODES);
    }

    // 4) x1 = relu(spmm(support1) + b1); also emits Afrag2 (bf16 fragment order)
    spmm128<<<N_NODES, 64, 0, stream>>>(rowinfo, erec, (const unsigned*)support1, b1, x1,
                                        (unsigned*)Afrag2);

    // 5) support2 = x1 @ W2 (bf16 out)
    mfma_gemm_frag<F_OUT, F_HID><<<(MT + 3) / 4, 256, 0, stream>>>(Afrag2, Bfrag2, support2, MT);

    // 6) x2 = spmm(support2) + b2
    spmm64<<<N_NODES, 64, 0, stream>>>(rowinfo, erec, support2, b2, x2);
}

// Round 11
// 315.157 us; speedup vs baseline: 1.2066x; 1.0565x over previous
//
#include <hip/hip_runtime.h>
#include <hip/hip_bf16.h>

#define N_NODES 50000
#define N_EDGES 1600000
#define F_IN    512
#define F_HID   128
#define F_OUT   64
#define NBUK    391          // ceil(50000/128) buckets of 128 nodes
#define EPB     2048         // edges per block in part_a (782 blocks)
#define CAP     4864         // per-bucket slot capacity (mean 4092, +12 sigma)
#define NPB_A   ((N_EDGES + EPB - 1) / EPB)   // 782

typedef short bf16x8 __attribute__((ext_vector_type(8)));
typedef float f32x4  __attribute__((ext_vector_type(4)));

__device__ __forceinline__ short f32_to_bf16(float f) {
    unsigned u = __float_as_uint(f);
    u += 0x7FFF + ((u >> 16) & 1);          // RTNE
    return (short)(u >> 16);
}
__device__ __forceinline__ float bf16_to_f32(short s) {
    return __uint_as_float(((unsigned)(unsigned short)s) << 16);
}
__device__ __forceinline__ float bf16lo(unsigned u) { return __uint_as_float(u << 16); }
__device__ __forceinline__ float bf16hi(unsigned u) { return __uint_as_float(u & 0xFFFF0000u); }

// 8x f32 -> bf16x8 via packed HW convert (RNE); 4 instrs instead of 24.
__device__ __forceinline__ bf16x8 cvt8(float4 lo, float4 hi) {
    union { unsigned u[4]; bf16x8 v; } r;
    asm("v_cvt_pk_bf16_f32 %0, %1, %2" : "=v"(r.u[0]) : "v"(lo.x), "v"(lo.y));
    asm("v_cvt_pk_bf16_f32 %0, %1, %2" : "=v"(r.u[1]) : "v"(lo.z), "v"(lo.w));
    asm("v_cvt_pk_bf16_f32 %0, %1, %2" : "=v"(r.u[2]) : "v"(hi.x), "v"(hi.y));
    asm("v_cvt_pk_bf16_f32 %0, %1, %2" : "=v"(r.u[3]) : "v"(hi.z), "v"(hi.w));
    return r.v;
}

// async global->LDS, 16B per lane; LDS dest = wave-uniform base + lane*16 (HW rule)
__device__ __forceinline__ void gload16(const void* g, void* l) {
    __builtin_amdgcn_global_load_lds((const __attribute__((address_space(1))) void*)g,
                                     (__attribute__((address_space(3))) void*)l, 16, 0, 0);
}

// B fragment unit u = (kc*NT + nt)*64 + lane:
//   holds W[k = kc*32 + (lane>>4)*8 + j][n = nt*16 + (lane&15)]  (W is [KD][NC] row-major)
template<int KD, int NC>
__device__ __forceinline__ void wtrans_one(const float* __restrict__ W,
                                           bf16x8* __restrict__ Bfrag, int u) {
    constexpr int NT = NC / 16;
    int lane = u & 63;
    int nt   = (u >> 6) % NT;
    int kc   = u / (64 * NT);
    int n = nt * 16 + (lane & 15);
    int k = kc * 32 + (lane >> 4) * 8;
    bf16x8 f;
    #pragma unroll
    for (int j = 0; j < 8; ++j) f[j] = f32_to_bf16(W[(size_t)(k + j) * NC + n]);
    Bfrag[u] = f;
}

// ---------------- fused launch A: part_a (blocks 0..NPB_A-1) + wtrans (rest) ----------------
// Independent phases merged by block-range: part_a writes gcnt/tmp; wtrans writes Bfrag1/2.

__global__ __launch_bounds__(256) void fused_aw(const int* __restrict__ dst,
                                                const int* __restrict__ src,
                                                const float* __restrict__ w,
                                                int* __restrict__ gcnt,
                                                uint2* __restrict__ tmp, int E,
                                                const float* __restrict__ W1,
                                                const float* __restrict__ W2,
                                                bf16x8* __restrict__ B1,
                                                bf16x8* __restrict__ B2) {
    const int tid = threadIdx.x;
    if (blockIdx.x < NPB_A) {
        // ---- part_a: LDS-binned bucket partition (round-9 verified) ----
        __shared__ int h[NBUK];
        __shared__ int base_[NBUK];
        __shared__ int ex[NBUK];
        __shared__ int curz[NBUK];
        __shared__ int   ldst[EPB];
        __shared__ uint2 rec[EPB];
        __shared__ int   tgt[EPB];
        for (int i = tid; i < NBUK; i += 256) { h[i] = 0; curz[i] = 0; }
        __syncthreads();
        int e0 = blockIdx.x * EPB;
        int e1 = min(e0 + EPB, E);
        int cnt = e1 - e0;
        for (int e = e0 + tid; e < e1; e += 256) {
            int d = dst[e];
            ldst[e - e0] = d;
            atomicAdd(&h[d >> 7], 1);
        }
        __syncthreads();
        for (int i = tid; i < NBUK; i += 256) {
            int c = h[i];
            base_[i] = c ? atomicAdd(&gcnt[i], c) : 0;
            ex[i] = c;
        }
        __syncthreads();
        for (int off = 1; off < NBUK; off <<= 1) {
            int i0 = tid, i1 = tid + 256;
            int t0 = 0, t1 = 0;
            if (i0 < NBUK && i0 >= off) t0 = ex[i0 - off];
            if (i1 < NBUK && i1 >= off) t1 = ex[i1 - off];
            __syncthreads();
            if (i0 < NBUK && i0 >= off) ex[i0] += t0;
            if (i1 < NBUK && i1 >= off) ex[i1] += t1;
            __syncthreads();
        }
        for (int e = e0 + tid; e < e1; e += 256) {
            int d = ldst[e - e0];
            int b = d >> 7;
            int j0 = atomicAdd(&curz[b], 1);
            int slot = ex[b] - h[b] + j0;
            rec[slot] = make_uint2(((unsigned)d << 16) | (unsigned)src[e],
                                   __float_as_uint(w[e]));
            int goff = base_[b] + j0;
            tgt[slot] = (goff < CAP) ? b * CAP + goff : -1;
        }
        __syncthreads();
        for (int i = tid; i < cnt; i += 256) {
            int t = tgt[i];
            if (t >= 0) tmp[t] = rec[i];
        }
    } else {
        // ---- wtrans: both weight conversions ----
        constexpr int U1 = (F_IN / 32) * (F_HID / 16) * 64;   // 8192
        constexpr int U2 = (F_HID / 32) * (F_OUT / 16) * 64;  // 1024
        int u = (blockIdx.x - NPB_A) * 256 + tid;
        if (u < U1) wtrans_one<F_IN, F_HID>(W1, B1, u);
        else if (u < U1 + U2) wtrans_one<F_HID, F_OUT>(W2, B2, u - U1);
    }
}

// ---------------- fused launch B: part_b (blocks 0..NBUK-1) + GEMM1 (rest) ----------------
// part_b writes rowinfo/erec; gemm1 writes support1 — independent. Shared 48KB arena.

__global__ __launch_bounds__(256) void fused_bg(const uint2* __restrict__ tmp,
                                                const int* __restrict__ gcnt,
                                                int2* __restrict__ rowinfo,
                                                uint2* __restrict__ erec,
                                                const float* __restrict__ X,
                                                const bf16x8* __restrict__ Bfrag,
                                                short* __restrict__ C, int Mrows) {
    __shared__ char arena[49152];
    const int tid = threadIdx.x;
    if (blockIdx.x < NBUK) {
        // ---- part_b: hist+scan+scatter in LDS, coalesced erec flush ----
        // (rec[] cache dropped to fit the 48KB arena: tmp re-read is L2-hot)
        int* s   = (int*)arena;                 // 128 ints
        int* cur = (int*)(arena + 512);         // 128 ints
        uint2* ord = (uint2*)(arena + 1024);    // CAP entries, 38912 B
        int b = blockIdx.x;
        int nb0 = b << 7;
        int r0 = b * CAP;
        int cnt_b = min(gcnt[b], CAP);
        if (tid < 128) s[tid] = 0;
        __syncthreads();
        for (int i = tid; i < cnt_b; i += 256)
            atomicAdd(&s[(tmp[r0 + i].x >> 16) - nb0], 1);
        __syncthreads();
        int v = (tid < 128) ? s[tid] : 0;
        #pragma unroll
        for (int off = 1; off < 128; off <<= 1) {
            int t = (tid >= off && tid < 128) ? s[tid - off] : 0;
            __syncthreads();
            if (tid < 128) s[tid] += t;
            __syncthreads();
        }
        if (tid < 128) {
            int ex = s[tid] - v;
            cur[tid] = ex;
            int node = nb0 + tid;
            if (node < N_NODES) rowinfo[node] = make_int2(r0 + ex, r0 + ex + v);
        }
        __syncthreads();
        for (int i = tid; i < cnt_b; i += 256) {
            uint2 r = tmp[r0 + i];
            int p = atomicAdd(&cur[(r.x >> 16) - nb0], 1);
            ord[p] = make_uint2(r.x & 0xFFFFu, r.y);
        }
        __syncthreads();
        for (int i = tid; i < cnt_b; i += 256)
            erec[r0 + i] = ord[i];
    } else {
        // ---- GEMM1: 3-deep LDS ring, counted vmcnt (round-9 verified body) ----
        constexpr int KD = F_IN, NC = F_HID;
        constexpr int S = KD / 32;            // 16 K-steps
        const int lane = tid & 63;
        const int wave = tid >> 6;
        const int wm = wave >> 1, wn = wave & 1;
        const int B0 = (blockIdx.x - NBUK) * 64;
        const int r_lo = lane & 15, cg = lane >> 4;

        int rowA = B0 + wave * 16 + r_lo;
        if (rowA > Mrows - 1) rowA = Mrows - 1;
        const char* gA = (const char*)(X + (size_t)rowA * KD) + cg * 32;
        const char* gB = (const char*)Bfrag + (size_t)(wave * 2) * 1024 + (size_t)lane * 16;

        const int dA0 = (0 * 256 + wave * 64) * 16;
        const int dA1 = (1 * 256 + wave * 64) * 16;
        const int dB0 = 8192 + (wave * 2 + 0) * 1024;
        const int dB1 = 8192 + (wave * 2 + 1) * 1024;

        f32x4 acc[2][4];
        #pragma unroll
        for (int m = 0; m < 2; ++m)
            #pragma unroll
            for (int n = 0; n < 4; ++n) acc[m][n] = (f32x4){0.f, 0.f, 0.f, 0.f};

        auto issue_stage = [&](int s_, char* L) {
            const char* a = gA + (size_t)s_ * 128;
            const char* b = gB + (size_t)s_ * 8192;
            gload16(a,        L + dA0);
            gload16(a + 16,   L + dA1);
            gload16(b,        L + dB0);
            gload16(b + 1024, L + dB1);
        };
        auto compute_step = [&](const char* L) {
            const char* A_ = L;
            const char* B_ = L + 8192;
            bf16x8 bb[4];
            #pragma unroll
            for (int n = 0; n < 4; ++n)
                bb[n] = *(const bf16x8*)(B_ + (wn * 4 + n) * 1024 + lane * 16);
            #pragma unroll
            for (int m = 0; m < 2; ++m) {
                int t = wm * 2 + m;
                float4 lo = *(const float4*)(A_ + (0 * 256 + t * 64 + lane) * 16);
                float4 hi = *(const float4*)(A_ + (1 * 256 + t * 64 + lane) * 16);
                bf16x8 a = cvt8(lo, hi);
                #pragma unroll
                for (int n = 0; n < 4; ++n)
                    acc[m][n] = __builtin_amdgcn_mfma_f32_16x16x32_bf16(a, bb[n], acc[m][n], 0, 0, 0);
            }
        };

        issue_stage(0, arena);
        issue_stage(1, arena + 16384);
        issue_stage(2, arena + 32768);

        for (int s_ = 0; s_ < S - 2; ++s_) {
            asm volatile("s_waitcnt vmcnt(8)" ::: "memory");
            asm volatile("s_barrier" ::: "memory");
            compute_step(arena + (s_ % 3) * 16384);
            asm volatile("s_barrier" ::: "memory");
            if (s_ + 3 < S) issue_stage(s_ + 3, arena + (s_ % 3) * 16384);
        }
        asm volatile("s_waitcnt vmcnt(4)" ::: "memory");
        asm volatile("s_barrier" ::: "memory");
        compute_step(arena + ((S - 2) % 3) * 16384);
        asm volatile("s_waitcnt vmcnt(0)" ::: "memory");
        asm volatile("s_barrier" ::: "memory");
        compute_step(arena + ((S - 1) % 3) * 16384);

        #pragma unroll
        for (int m = 0; m < 2; ++m) {
            int tile16 = (B0 >> 4) + wm * 2 + m;
            if (tile16 * 16 < Mrows) {
                #pragma unroll
                for (int n = 0; n < 4; ++n) {
                    #pragma unroll
                    for (int r = 0; r < 4; ++r) {
                        int grow = tile16 * 16 + cg * 4 + r;
                        C[(size_t)grow * NC + (wn * 4 + n) * 16 + r_lo] = f32_to_bf16(acc[m][n][r]);
                    }
                }
            }
        }
    }
}

// ---------------- fragment MFMA GEMM (A already in fragment order, bf16) ----------------

template<int NC, int KD>
__global__ __launch_bounds__(256) void mfma_gemm_frag(const bf16x8* __restrict__ Afrag,
                                                      const bf16x8* __restrict__ Bfrag,
                                                      short* __restrict__ C, int Mt) {
    constexpr int NT = NC / 16, KC = KD / 32;
    constexpr int PFA = (KC < 4) ? KC : 4;
    const int lane = threadIdx.x & 63;
    const int wave = threadIdx.x >> 6;
    const int tile = blockIdx.x * 4 + wave;
    if (tile >= Mt) return;

    const bf16x8* ap = Afrag + (size_t)tile * KC * 64 + lane;
    const bf16x8* bp = Bfrag + lane;

    f32x4 acc[NT];
    #pragma unroll
    for (int i = 0; i < NT; ++i) acc[i] = (f32x4){0.f, 0.f, 0.f, 0.f};

    bf16x8 abuf[PFA];
    #pragma unroll
    for (int i = 0; i < PFA; ++i) abuf[i] = ap[(size_t)i * 64];
    bf16x8 bbuf[NT];
    #pragma unroll
    for (int nt = 0; nt < NT; ++nt) bbuf[nt] = bp[(size_t)nt * 64];

    #pragma unroll
    for (int kc = 0; kc < KC; ++kc) {
        bf16x8 a = abuf[kc % PFA];
        int ka = kc + PFA; if (ka > KC - 1) ka = KC - 1;
        abuf[kc % PFA] = ap[(size_t)ka * 64];
        int kb = (kc + 1 < KC) ? kc + 1 : kc;
        bf16x8 bnew[NT];
        #pragma unroll
        for (int nt = 0; nt < NT; ++nt) {
            bnew[nt] = bp[((size_t)kb * NT + nt) * 64];
            acc[nt] = __builtin_amdgcn_mfma_f32_16x16x32_bf16(a, bbuf[nt], acc[nt], 0, 0, 0);
        }
        #pragma unroll
        for (int nt = 0; nt < NT; ++nt) bbuf[nt] = bnew[nt];
    }

    const int lrow = lane & 15, kgrp = lane >> 4;
    #pragma unroll
    for (int nt = 0; nt < NT; ++nt) {
        #pragma unroll
        for (int r = 0; r < 4; ++r) {
            int grow = tile * 16 + kgrp * 4 + r;
            C[(size_t)grow * NC + nt * 16 + lrow] = f32_to_bf16(acc[nt][r]);
        }
    }
}

// ---------------- SpMM gather ----------------

// F=128: one wave per node. 8-wide UNMASKED main loop, software-pipelined.
__global__ __launch_bounds__(64) void spmm128(const int2* __restrict__ rowinfo,
                                              const uint2* __restrict__ erec,
                                              const unsigned* __restrict__ featu,
                                              const float* __restrict__ bias,
                                              float* __restrict__ out,
                                              unsigned* __restrict__ afrag2u) {
    int d = blockIdx.x, tid = threadIdx.x;
    int2 ri = rowinfo[d];
    int beg = ri.x, end = ri.y;
    float a0 = 0.f, a1 = 0.f;
    const unsigned* fp = featu + tid;
    int e = beg;
    if (end - beg >= 8) {
        uint2 r[8];
        #pragma unroll
        for (int j = 0; j < 8; ++j) r[j] = erec[e + j];
        for (; e + 16 <= end; e += 8) {
            unsigned f[8];
            #pragma unroll
            for (int j = 0; j < 8; ++j) f[j] = fp[r[j].x * 64u];
            uint2 rn[8];
            #pragma unroll
            for (int j = 0; j < 8; ++j) rn[j] = erec[e + 8 + j];
            #pragma unroll
            for (int j = 0; j < 8; ++j) {
                float w = __uint_as_float(r[j].y);
                a0 += w * bf16lo(f[j]);
                a1 += w * bf16hi(f[j]);
            }
            #pragma unroll
            for (int j = 0; j < 8; ++j) r[j] = rn[j];
        }
        {   // drain: last full batch, no prefetch
            unsigned f[8];
            #pragma unroll
            for (int j = 0; j < 8; ++j) f[j] = fp[r[j].x * 64u];
            #pragma unroll
            for (int j = 0; j < 8; ++j) {
                float w = __uint_as_float(r[j].y);
                a0 += w * bf16lo(f[j]);
                a1 += w * bf16hi(f[j]);
            }
            e += 8;
        }
    }
    for (; e + 4 <= end; e += 4) {
        uint2 r0 = erec[e], r1 = erec[e + 1], r2 = erec[e + 2], r3 = erec[e + 3];
        unsigned f0 = fp[r0.x * 64u];
        unsigned f1 = fp[r1.x * 64u];
        unsigned f2 = fp[r2.x * 64u];
        unsigned f3 = fp[r3.x * 64u];
        float w0 = __uint_as_float(r0.y), w1 = __uint_as_float(r1.y);
        float w2 = __uint_as_float(r2.y), w3 = __uint_as_float(r3.y);
        a0 += w0 * bf16lo(f0); a1 += w0 * bf16hi(f0);
        a0 += w1 * bf16lo(f1); a1 += w1 * bf16hi(f1);
        a0 += w2 * bf16lo(f2); a1 += w2 * bf16hi(f2);
        a0 += w3 * bf16lo(f3); a1 += w3 * bf16hi(f3);
    }
    for (; e < end; ++e) {
        uint2 r = erec[e];
        unsigned f = fp[r.x * 64u];
        float w = __uint_as_float(r.y);
        a0 += w * bf16lo(f); a1 += w * bf16hi(f);
    }
    float ox = fmaxf(a0 + bias[2 * tid], 0.f);
    float oy = fmaxf(a1 + bias[2 * tid + 1], 0.f);
    *(float2*)&out[(size_t)d * 128 + 2 * tid] = make_float2(ox, oy);
    unsigned packed = (unsigned)(unsigned short)f32_to_bf16(ox) |
                      ((unsigned)(unsigned short)f32_to_bf16(oy) << 16);
    int unit = ((d >> 4) * 4 + (tid >> 4)) * 64 + ((tid >> 2) & 3) * 16 + (d & 15);
    afrag2u[unit * 4 + (tid & 3)] = packed;
}

// F=64: one wave per node, same pipelined 8-wide structure.
__global__ __launch_bounds__(64) void spmm64(const int2* __restrict__ rowinfo,
                                             const uint2* __restrict__ erec,
                                             const short* __restrict__ feat,
                                             const float* __restrict__ bias,
                                             float* __restrict__ out) {
    int d = blockIdx.x, tid = threadIdx.x;
    int2 ri = rowinfo[d];
    int beg = ri.x, end = ri.y;
    float acc = 0.f;
    const short* fp = feat + tid;
    int e = beg;
    if (end - beg >= 8) {
        uint2 r[8];
        #pragma unroll
        for (int j = 0; j < 8; ++j) r[j] = erec[e + j];
        for (; e + 16 <= end; e += 8) {
            float f[8];
            #pragma unroll
            for (int j = 0; j < 8; ++j) f[j] = bf16_to_f32(fp[r[j].x * 64u]);
            uint2 rn[8];
            #pragma unroll
            for (int j = 0; j < 8; ++j) rn[j] = erec[e + 8 + j];
            #pragma unroll
            for (int j = 0; j < 8; ++j) acc += __uint_as_float(r[j].y) * f[j];
            #pragma unroll
            for (int j = 0; j < 8; ++j) r[j] = rn[j];
        }
        {
            float f[8];
            #pragma unroll
            for (int j = 0; j < 8; ++j) f[j] = bf16_to_f32(fp[r[j].x * 64u]);
            #pragma unroll
            for (int j = 0; j < 8; ++j) acc += __uint_as_float(r[j].y) * f[j];
            e += 8;
        }
    }
    for (; e + 4 <= end; e += 4) {
        uint2 r0 = erec[e], r1 = erec[e + 1], r2 = erec[e + 2], r3 = erec[e + 3];
        float f0 = bf16_to_f32(fp[r0.x * 64u]);
        float f1 = bf16_to_f32(fp[r1.x * 64u]);
        float f2 = bf16_to_f32(fp[r2.x * 64u]);
        float f3 = bf16_to_f32(fp[r3.x * 64u]);
        acc += __uint_as_float(r0.y) * f0;
        acc += __uint_as_float(r1.y) * f1;
        acc += __uint_as_float(r2.y) * f2;
        acc += __uint_as_float(r3.y) * f3;
    }
    for (; e < end; ++e) {
        uint2 r = erec[e];
        acc += __uint_as_float(r.y) * bf16_to_f32(fp[r.x * 64u]);
    }
    out[(size_t)d * 64 + tid] = acc + bias[tid];
}

// ---------------- launch ----------------

extern "C" void kernel_launch(void* const* d_in, const int* in_sizes, int n_in,
                              void* d_out, int out_size, void* d_ws, size_t ws_size,
                              hipStream_t stream) {
    const float* x  = (const float*)d_in[0];
    const int*   ei = (const int*)d_in[1];
    const float* ew = (const float*)d_in[2];
    const float* W1 = (const float*)d_in[3];
    const float* b1 = (const float*)d_in[4];
    const float* W2 = (const float*)d_in[5];
    const float* b2 = (const float*)d_in[6];

    const int* dst = ei;
    const int* src = ei + N_EDGES;

    float* x1 = (float*)d_out;                          // [50000,128] fp32
    float* x2 = x1 + (size_t)N_NODES * F_HID;           // [50000,64]  fp32

    char* ws = (char*)d_ws;
    uint2*  erec     = (uint2*)ws;  ws += (size_t)NBUK * CAP * 8;         // 15.2 MB (slotted)
    uint2*  tmp      = (uint2*)ws;  ws += (size_t)NBUK * CAP * 8;         // 15.2 MB (slotted)
    short*  support1 = (short*)ws;  ws += (size_t)N_NODES * F_HID * 2;    // 12.8 MB
    short*  support2 = (short*)ws;  ws += (size_t)N_NODES * F_OUT * 2;    //  6.4 MB
    bf16x8* Afrag2   = (bf16x8*)ws; ws += (size_t)N_NODES * F_HID * 2;    // 12.8 MB
    bf16x8* Bfrag1   = (bf16x8*)ws; ws += (size_t)F_HID * F_IN * 2;       //  128 KB
    bf16x8* Bfrag2   = (bf16x8*)ws; ws += (size_t)F_OUT * F_HID * 2;      //   16 KB
    int2*   rowinfo  = (int2*)ws;   ws += (size_t)N_NODES * 8;            //  400 KB
    int*    gcnt     = (int*)ws;    ws += 400 * 4;

    const int MT = N_NODES / 16;                        // 3125 row tiles (exact)
    const int GB = (N_NODES + 63) / 64;                 // 782 gemm1 blocks

    // 1) part_a ∥ wtrans  (independent: gcnt/tmp vs Bfrag1/2)
    hipMemsetAsync(gcnt, 0, NBUK * sizeof(int), stream);
    fused_aw<<<NPB_A + 36, 256, 0, stream>>>(dst, src, ew, gcnt, tmp, N_EDGES,
                                             W1, W2, Bfrag1, Bfrag2);

    // 2) part_b ∥ gemm1  (independent: rowinfo/erec vs support1)
    fused_bg<<<NBUK + GB, 256, 0, stream>>>(tmp, gcnt, rowinfo, erec,
                                            x, Bfrag1, support1, N_NODES);

    // 3) x1 = relu(spmm(support1) + b1); also emits Afrag2 (bf16 fragment order)
    spmm128<<<N_NODES, 64, 0, stream>>>(rowinfo, erec, (const unsigned*)support1, b1, x1,
                                        (unsigned*)Afrag2);

    // 4) support2 = x1 @ W2 (bf16 out)
    mfma_gemm_frag<F_OUT, F_HID><<<(MT + 3) / 4, 256, 0, stream>>>(Afrag2, Bfrag2, support2, MT);

    // 5) x2 = spmm(support2) + b2
    spmm64<<<N_NODES, 64, 0, stream>>>(rowinfo, erec, support2, b2, x2);
}